// Round 6
// baseline (325.275 us; speedup 1.0000x reference)
//
#include <hip/hip_runtime.h>
#include <hip/hip_bf16.h>

// MHA: B=4 S=2048 D=768 H=12 K=V=64, fp32 in/out, bf16 MFMA internally.
// R10: GEMM overhaul to the m97 structure (global_load_lds staging).
//  - cast_kernel: q/k/v fp32 -> bf16 once (qb/kb/vb). All GEMM operands
//    are then linear bf16 -> width-16 global_load_lds staging (no VGPR
//    round-trip, no per-tile cast VALU). Linear [128][64] LDS tiles.
//  - Workspace: qb in bias-slack; kb aliases OFF_O (dead before attn
//    writes O); vb uses d_out as scratch (gemm_out overwrites all of
//    d_out last). No new workspace.
//  - attn3 unchanged from R9 (104 us, VALU-throughput-limited).
// Numerics: identical f2bf rounding + MFMA order -> absmax unchanged.

typedef __attribute__((ext_vector_type(8))) short short8;
typedef __attribute__((ext_vector_type(4))) short s16x4;
typedef __attribute__((ext_vector_type(4))) float f32x4;
typedef __attribute__((ext_vector_type(16))) float f32x16;
typedef __attribute__((ext_vector_type(2))) int int2v;
typedef __attribute__((ext_vector_type(4))) int int4v;

#define NB 4
#define NS 2048
#define ND 768
#define NH 12
#define HD 64

#define QSCALE 0.18033688011112043f     /* 0.125 * log2(e): folded into Q */
#define NLOG2E (-1.4426950408889634e9f) /* -1e9 * log2(e)                 */

__device__ __forceinline__ unsigned short f2bf(float f){
    __hip_bfloat16 h = __float2bfloat16(f);
    return __builtin_bit_cast(unsigned short, h);
}

__device__ __forceinline__ void gload16(const void* g, void* l){
    __builtin_amdgcn_global_load_lds(
        (const __attribute__((address_space(1))) void*)g,
        (__attribute__((address_space(3))) void*)l, 16, 0, 0);
}

// ---------------- workspace layout (bytes) ----------------
#define OFF_BIAS ((size_t)0)          // fp32 [2048][2048] log2-domain bias (16.8 MB)
#define OFF_QB  ((size_t)16777216)    // [B*S,768] bf16 queries (12.6 MB, bias slack)
#define OFF_FLAG ((size_t)33554432)   // u32: 1 if any bias value nonzero
#define OFF_WQ  ((size_t)37748736)
#define OFF_WK  ((size_t)38928384)
#define OFF_WV  ((size_t)40108032)
#define OFF_WO  ((size_t)41287680)
#define OFF_Q   ((size_t)42467328)   // [B,H,S,64] bf16, pre-scaled by QSCALE
#define OFF_K   ((size_t)55050240)   // [B,H,S,64] bf16
#define OFF_V   ((size_t)67633152)   // [B,H,64,S] bf16 (V^T)
#define OFF_O   ((size_t)80216064)   // [B,H,S,64]; ALSO kb scratch pre-attn
// kb = ws+OFF_O (dead before attn writes O); vb = d_out scratch.

// ---------------- prep: bias[q][m] = (1-mask)*(-1e9)*log2e, fp32 --------
__global__ __launch_bounds__(256) void bias_kernel(
    const float* __restrict__ mask, float* __restrict__ biasf,
    unsigned* __restrict__ flag){
    size_t t = (size_t)blockIdx.x*256 + threadIdx.x;
    f32x4 a = reinterpret_cast<const f32x4*>(mask)[2*t];
    f32x4 b = reinterpret_cast<const f32x4*>(mask)[2*t+1];
    f32x4 oa, ob;
    bool nz = false;
    for(int i=0;i<4;i++){
        oa[i] = (1.0f-a[i])*NLOG2E; ob[i] = (1.0f-b[i])*NLOG2E;
        nz = nz || (oa[i] != 0.0f) || (ob[i] != 0.0f);
    }
    reinterpret_cast<f32x4*>(biasf)[2*t]   = oa;
    reinterpret_cast<f32x4*>(biasf)[2*t+1] = ob;
    if(nz) atomicOr(flag, 1u);
}

// ---------------- prep: q/k/v fp32 -> bf16 ----------------
__global__ __launch_bounds__(256) void cast_kernel(
    const float* __restrict__ q, const float* __restrict__ k,
    const float* __restrict__ v, unsigned short* __restrict__ qb,
    unsigned short* __restrict__ kb, unsigned short* __restrict__ vb){
    int y = blockIdx.y;
    const float* src = y==0 ? q : (y==1 ? k : v);
    unsigned short* dst = y==0 ? qb : (y==1 ? kb : vb);
    size_t t = (size_t)blockIdx.x*256 + threadIdx.x;
    f32x4 a = reinterpret_cast<const f32x4*>(src)[2*t];
    f32x4 b = reinterpret_cast<const f32x4*>(src)[2*t+1];
    short8 o;
    o[0]=(short)f2bf(a[0]); o[1]=(short)f2bf(a[1]); o[2]=(short)f2bf(a[2]); o[3]=(short)f2bf(a[3]);
    o[4]=(short)f2bf(b[0]); o[5]=(short)f2bf(b[1]); o[6]=(short)f2bf(b[2]); o[7]=(short)f2bf(b[3]);
    reinterpret_cast<short8*>(dst)[t] = o;
}

// ---------------- prep: tiled transpose-cast of weights ----------------
__global__ __launch_bounds__(256) void packw_kernel(
    const float* __restrict__ Wq, const float* __restrict__ Wk,
    const float* __restrict__ Wv, const float* __restrict__ Wo,
    unsigned short* __restrict__ wq, unsigned short* __restrict__ wk,
    unsigned short* __restrict__ wv, unsigned short* __restrict__ wo,
    unsigned* __restrict__ flag){
    if(blockIdx.x==0 && blockIdx.y==0 && threadIdx.x==0) *flag = 0u;
    int y = blockIdx.y, x = blockIdx.x;
    const float* src; unsigned short* dst; int sstr, r0, c0;
    if(y < 3){
        const float* W = y==0 ? Wq : (y==1 ? Wk : Wv);
        unsigned short* o = y==0 ? wq : (y==1 ? wk : wv);
        int h = x/12, dt = x%12;
        src = W + (size_t)h*ND*HD; sstr = HD; r0 = dt*64; c0 = 0;
        dst = o + (size_t)h*HD*ND;
    } else {
        src = Wo; sstr = ND; r0 = (x/12)*64; c0 = (x%12)*64;
        dst = wo;
    }
    __shared__ unsigned short T[64*68];
    int t = threadIdx.x;
    int tr = t>>4, tc4 = (t&15)*4;
    for(int it=0; it<4; it++){
        int r = it*16 + tr;
        f32x4 vv = *reinterpret_cast<const f32x4*>(src + (size_t)(r0+r)*sstr + c0 + tc4);
        s16x4 p; p[0]=(short)f2bf(vv[0]); p[1]=(short)f2bf(vv[1]);
                 p[2]=(short)f2bf(vv[2]); p[3]=(short)f2bf(vv[3]);
        *reinterpret_cast<s16x4*>(&T[r*68 + tc4]) = p;
    }
    __syncthreads();
    for(int it=0; it<4; it++){
        int c = it*16 + tr;
        s16x4 p;
        p[0] = (short)T[(tc4+0)*68 + c];
        p[1] = (short)T[(tc4+1)*68 + c];
        p[2] = (short)T[(tc4+2)*68 + c];
        p[3] = (short)T[(tc4+3)*68 + c];
        *reinterpret_cast<s16x4*>(dst + (size_t)(c0+c)*ND + r0 + tc4) = p;
    }
}

// ---------------- Q/K projections: C[128x128] = qb/kb * Wt^T (all bf16) --
#define CPT 136
__global__ __launch_bounds__(256) void gemm_proj(
    const unsigned short* __restrict__ qb, const unsigned short* __restrict__ kb,
    const unsigned short* __restrict__ wq, const unsigned short* __restrict__ wk,
    unsigned short* __restrict__ oq, unsigned short* __restrict__ ok){
    int z = blockIdx.z;
    const unsigned short* Af = z==0 ? qb : kb;
    const unsigned short* Bt = z==0 ? wq : wk;
    unsigned short* dst      = z==0 ? oq : ok;
    const float qsc          = z==0 ? QSCALE : 1.0f;

    __shared__ alignas(16) unsigned short smem[128*CPT]; // 34816 B (As+Bs=32K; Cs=34.8K)
    unsigned short* As = smem;            // [128][64] linear
    unsigned short* Bs = smem + 128*64;   // [128][64] linear
    int tid = threadIdx.x;
    int lane = tid & 63, wave = tid >> 6;
    int l15 = lane & 15, quad = lane >> 4;
    int wm = (wave >> 1)*64, wn = (wave & 1)*64;
    int tm = blockIdx.x*128, tn = blockIdx.y*128;

    f32x4 acc[4][4] = {};
    for(int k0 = 0; k0 < ND; k0 += 64){
        __syncthreads();
        const unsigned short* ga = Af + (size_t)(tm + wave*32 + (lane>>3))*ND + k0 + (lane&7)*8;
        const unsigned short* gb = Bt + (size_t)(tn + wave*32 + (lane>>3))*ND + k0 + (lane&7)*8;
        #pragma unroll
        for(int it=0; it<4; it++){
            gload16(ga + (size_t)(it*8)*ND, &As[(wave*32+it*8)*64]);
            gload16(gb + (size_t)(it*8)*ND, &Bs[(wave*32+it*8)*64]);
        }
        __syncthreads();
        for(int ks = 0; ks < 2; ks++){
            short8 af[4], bf[4];
            for(int i = 0; i < 4; i++)
                af[i] = *reinterpret_cast<const short8*>(&As[(wm + i*16 + l15)*64 + ks*32 + quad*8]);
            for(int j = 0; j < 4; j++)
                bf[j] = *reinterpret_cast<const short8*>(&Bs[(wn + j*16 + l15)*64 + ks*32 + quad*8]);
            for(int i = 0; i < 4; i++)
                for(int j = 0; j < 4; j++)
                    acc[i][j] = __builtin_amdgcn_mfma_f32_16x16x32_bf16(af[i], bf[j], acc[i][j], 0, 0, 0);
        }
    }
    __syncthreads();
    unsigned short* Cs = smem;   // [128][CPT]
    for(int i = 0; i < 4; i++)
        for(int j = 0; j < 4; j++)
            for(int r = 0; r < 4; r++)
                Cs[(wm + i*16 + quad*4 + r)*CPT + wn + j*16 + l15] = f2bf(acc[i][j][r]*qsc);
    __syncthreads();
    for(int c8 = 0; c8 < 8; c8++){
        int idx = c8*256 + tid;
        int row = idx >> 4, ch = idx & 15;
        short8 val = *reinterpret_cast<const short8*>(&Cs[row*CPT + ch*8]);
        int m = tm + row, n = tn + ch*8;
        int b = m >> 11, s = m & 2047, h = n >> 6, kk = n & 63;
        *reinterpret_cast<short8*>(dst + ((size_t)(b*NH + h)*NS + s)*HD + kk) = val;
    }
}

// ---------------- V^T projection (operand-swapped): A=wv, B=vb (bf16) ----
__global__ __launch_bounds__(256) void gemm_projT(
    const unsigned short* __restrict__ A,   // wv [768][768]  (rows = h*64+kk)
    const unsigned short* __restrict__ Bv,  // vb [8192][768] bf16
    unsigned short* __restrict__ dst){      // vtws [48][64][2048]
    __shared__ alignas(16) unsigned short smem[128*CPT];
    unsigned short* As = smem;
    unsigned short* Bs = smem + 128*64;
    int tid = threadIdx.x;
    int lane = tid & 63, wave = tid >> 6;
    int l15 = lane & 15, quad = lane >> 4;
    int wm = (wave >> 1)*64, wn = (wave & 1)*64;
    int tm = blockIdx.x*128, tn = blockIdx.y*128;

    f32x4 acc[4][4] = {};
    for(int k0 = 0; k0 < ND; k0 += 64){
        __syncthreads();
        const unsigned short* ga = A  + (size_t)(tm + wave*32 + (lane>>3))*ND + k0 + (lane&7)*8;
        const unsigned short* gb = Bv + (size_t)(tn + wave*32 + (lane>>3))*ND + k0 + (lane&7)*8;
        #pragma unroll
        for(int it=0; it<4; it++){
            gload16(ga + (size_t)(it*8)*ND, &As[(wave*32+it*8)*64]);
            gload16(gb + (size_t)(it*8)*ND, &Bs[(wave*32+it*8)*64]);
        }
        __syncthreads();
        for(int ks = 0; ks < 2; ks++){
            short8 af[4], bf[4];
            for(int i = 0; i < 4; i++)
                af[i] = *reinterpret_cast<const short8*>(&As[(wm + i*16 + l15)*64 + ks*32 + quad*8]);
            for(int j = 0; j < 4; j++)
                bf[j] = *reinterpret_cast<const short8*>(&Bs[(wn + j*16 + l15)*64 + ks*32 + quad*8]);
            for(int i = 0; i < 4; i++)
                for(int j = 0; j < 4; j++)
                    acc[i][j] = __builtin_amdgcn_mfma_f32_16x16x32_bf16(af[i], bf[j], acc[i][j], 0, 0, 0);
        }
    }
    __syncthreads();
    unsigned short* Cs = smem;   // [128 rows=m][CPT cols=n]
    for(int i = 0; i < 4; i++)
        for(int j = 0; j < 4; j++)
            for(int r = 0; r < 4; r++)
                Cs[(wm + i*16 + quad*4 + r)*CPT + wn + j*16 + l15] = f2bf(acc[i][j][r]);
    __syncthreads();
    int b = tn >> 11, s0 = tn & 2047;
    for(int c8 = 0; c8 < 8; c8++){
        int idx = c8*256 + tid;
        int row = idx >> 4, ch = idx & 15;
        short8 val = *reinterpret_cast<const short8*>(&Cs[row*CPT + ch*8]);
        int h = (tm + row) >> 6, kk = (tm + row) & 63;
        *reinterpret_cast<short8*>(dst + ((size_t)(b*NH + h)*HD + kk)*NS + s0 + ch*8) = val;
    }
}

// ---------------- flash attention: 32x32 MFMA, in-reg softmax, pipelined --
// (unchanged from R9)
__global__ __launch_bounds__(256, 3) void attn3_kernel(
    const unsigned short* __restrict__ qws, const unsigned short* __restrict__ kws,
    const unsigned short* __restrict__ vtws, const float* __restrict__ biasf,
    const unsigned* __restrict__ bflag, unsigned short* __restrict__ ows){
    const int bh = blockIdx.y, qt = blockIdx.x;
    const int tid = threadIdx.x, lane = tid & 63, wave = tid >> 6;
    const int l31 = lane & 31, hi = lane >> 5;

    __shared__ alignas(16) unsigned short Ks[2][64*72];   // 18432 B
    __shared__ alignas(16) unsigned short Vs[3][64*72];   // 27648 B (total 46080)

    const size_t bhq = (size_t)bh * NS;
    const int qb0 = qt*128 + wave*32;
    const bool hasBias = (*bflag != 0u);   // uniform

    short8 bq[4];
    #pragma unroll
    for(int ds=0; ds<4; ds++)
        bq[ds] = *reinterpret_cast<const short8*>(
            qws + (bhq + qb0 + l31)*HD + ds*16 + hi*8);

    const float* bp = biasf + (size_t)(qb0 + l31)*NS + hi*4;

    const int rS = tid >> 3;       // 0..31
    const int cS = tid & 7;        // 0..7

    short8 rk[2], rv[2];
    #define LOADK(i,KT) rk[i] = *reinterpret_cast<const short8*>(kws + (bhq + (size_t)(KT)*64 + (i)*32 + rS)*HD + cS*8)
    #define LOADV(i,KT) rv[i] = *reinterpret_cast<const short8*>(vtws + ((size_t)bh*HD + (i)*32 + rS)*NS + (size_t)(KT)*64 + cS*8)

    #define STAGE(KB, VB)                                                         \
    {                                                                             \
        _Pragma("unroll")                                                         \
        for(int i=0;i<2;i++){                                                     \
            int row = i*32 + rS;                                                  \
            *reinterpret_cast<short8*>(&Ks[KB][row*72 + cS*8]) = rk[i];           \
            *reinterpret_cast<short8*>(&Vs[VB][row*72 + cS*8]) = rv[i];           \
        }                                                                         \
    }

    #define QK(KB)                                                                \
    {                                                                             \
        _Pragma("unroll")                                                         \
        for(int kb=0; kb<2; kb++){                                                \
            f32x16 zt = {};                                                       \
            _Pragma("unroll")                                                     \
            for(int ds=0; ds<4; ds++){                                            \
                short8 ak = *reinterpret_cast<const short8*>(                     \
                    &Ks[KB][(kb*32 + l31)*72 + ds*16 + hi*8]);                    \
                zt = __builtin_amdgcn_mfma_f32_32x32x16_bf16(ak, bq[ds], zt, 0, 0, 0);\
            }                                                                     \
            z2[kb] = zt;                                                          \
        }                                                                         \
    }

    #define SMAX(KT)                                                              \
    {                                                                             \
        _Pragma("unroll")                                                         \
        for(int kb=0; kb<2; kb++){                                                \
            f32x4 bb[4];                                                          \
            if(hasBias){                                                          \
                _Pragma("unroll")                                                 \
                for(int g=0; g<4; g++)                                            \
                    bb[g] = *reinterpret_cast<const f32x4*>(bp + (KT)*64 + kb*32 + g*8);\
            } else {                                                              \
                _Pragma("unroll")                                                 \
                for(int g=0; g<4; g++){ bb[g][0]=0.f; bb[g][1]=0.f; bb[g][2]=0.f; bb[g][3]=0.f; } \
            }                                                                     \
            unsigned p[8];                                                        \
            _Pragma("unroll")                                                     \
            for(int g=0; g<4; g++){                                               \
                float e0 = exp2f(z2[kb][g*4+0] + bb[g][0]);                       \
                float e1 = exp2f(z2[kb][g*4+1] + bb[g][1]);                       \
                float e2 = exp2f(z2[kb][g*4+2] + bb[g][2]);                       \
                float e3 = exp2f(z2[kb][g*4+3] + bb[g][3]);                       \
                p[g*2+0] = (unsigned)f2bf(e0) | ((unsigned)f2bf(e1) << 16);       \
                p[g*2+1] = (unsigned)f2bf(e2) | ((unsigned)f2bf(e3) << 16);       \
            }                                                                     \
            int2v sA = __builtin_amdgcn_permlane32_swap((int)p[0], (int)p[2], false, false); \
            int2v sB = __builtin_amdgcn_permlane32_swap((int)p[1], (int)p[3], false, false); \
            int2v sC = __builtin_amdgcn_permlane32_swap((int)p[4], (int)p[6], false, false); \
            int2v sD = __builtin_amdgcn_permlane32_swap((int)p[5], (int)p[7], false, false); \
            int4v f0; f0[0]=sA[0]; f0[1]=sB[0]; f0[2]=sA[1]; f0[3]=sB[1];         \
            int4v f1; f1[0]=sC[0]; f1[1]=sD[0]; f1[2]=sC[1]; f1[3]=sD[1];         \
            afragP[kb*2+0] = __builtin_bit_cast(short8, f0);                      \
            afragP[kb*2+1] = __builtin_bit_cast(short8, f1);                      \
        }                                                                         \
    }

    #define PVACC(VB)                                                             \
    {                                                                             \
        _Pragma("unroll")                                                         \
        for(int kst=0; kst<4; kst++){                                             \
            zacc = __builtin_amdgcn_mfma_f32_32x32x16_bf16(afragP[kst], vone, zacc, 0, 0, 0); \
            _Pragma("unroll")                                                     \
            for(int nb=0; nb<2; nb++){                                            \
                short8 bv = *reinterpret_cast<const short8*>(                     \
                    &Vs[VB][(nb*32 + l31)*72 + kst*16 + hi*8]);                   \
                oacc[nb] = __builtin_amdgcn_mfma_f32_32x32x16_bf16(afragP[kst], bv, oacc[nb], 0, 0, 0); \
            }                                                                     \
        }                                                                         \
    }

    f32x16 oacc[2] = {};
    f32x16 zacc = {};
    f32x16 z2[2];
    short8 afragP[4];
    short8 vone;
    #pragma unroll
    for(int i=0;i<8;i++) vone[i] = (short)0x3F80;   // bf16 1.0

    LOADK(0,0); LOADK(1,0); LOADV(0,0); LOADV(1,0);
    STAGE(0, 0)
    __syncthreads();
    LOADK(0,1); LOADK(1,1); LOADV(0,1); LOADV(1,1);
    __builtin_amdgcn_s_setprio(1);
    QK(0)
    __builtin_amdgcn_s_setprio(0);
    SMAX(0)

    for(int kt = 1; kt < 32; kt++){
        const int cb = kt & 1;
        const int vb = kt % 3;
        const int vp = (kt-1) % 3;
        STAGE(cb, vb)
        __syncthreads();
        int ktn = kt < 31 ? kt+1 : 31;
        LOADK(0,ktn); LOADK(1,ktn); LOADV(0,ktn); LOADV(1,ktn);

        __builtin_amdgcn_s_setprio(1);
        QK(cb)
        PVACC(vp)
        __builtin_amdgcn_s_setprio(0);
        SMAX(kt)
    }
    {
        const int vp = 31 % 3;   // = 1
        __builtin_amdgcn_s_setprio(1);
        PVACC(vp)
        __builtin_amdgcn_s_setprio(0);
    }

    float inv[16];
    #pragma unroll
    for(int r=0;r<16;r++) inv[r] = 1.0f / zacc[r];
    #pragma unroll
    for(int nb=0;nb<2;nb++)
        #pragma unroll
        for(int r=0;r<16;r++){
            int q = qb0 + (r&3) + 8*(r>>2) + 4*hi;
            ows[(bhq + q)*HD + nb*32 + l31] = f2bf(oacc[nb][r]*inv[r]);
        }
    #undef LOADK
    #undef LOADV
    #undef STAGE
    #undef QK
    #undef SMAX
    #undef PVACC
}

// ---------------- output projection: fp32 out (bf16 x bf16) ----------------
__global__ __launch_bounds__(256) void gemm_out(
    const unsigned short* __restrict__ A, const unsigned short* __restrict__ Bt,
    float* __restrict__ out){
    __shared__ alignas(16) unsigned short smem[2*128*64]; // 32768 B
    unsigned short* As = smem;
    unsigned short* Bs = smem + 128*64;
    int tid = threadIdx.x;
    int lane = tid & 63, wave = tid >> 6;
    int l15 = lane & 15, quad = lane >> 4;
    int wm = (wave >> 1)*64, wn = (wave & 1)*64;
    int tm = blockIdx.x*128, tn = blockIdx.y*128;

    f32x4 acc[4][4] = {};
    for(int k0 = 0; k0 < ND; k0 += 64){
        __syncthreads();
        const unsigned short* ga = A  + (size_t)(tm + wave*32 + (lane>>3))*ND + k0 + (lane&7)*8;
        const unsigned short* gb = Bt + (size_t)(tn + wave*32 + (lane>>3))*ND + k0 + (lane&7)*8;
        #pragma unroll
        for(int it=0; it<4; it++){
            gload16(ga + (size_t)(it*8)*ND, &As[(wave*32+it*8)*64]);
            gload16(gb + (size_t)(it*8)*ND, &Bs[(wave*32+it*8)*64]);
        }
        __syncthreads();
        for(int ks = 0; ks < 2; ks++){
            short8 af[4], bf[4];
            for(int i = 0; i < 4; i++)
                af[i] = *reinterpret_cast<const short8*>(&As[(wm + i*16 + l15)*64 + ks*32 + quad*8]);
            for(int j = 0; j < 4; j++)
                bf[j] = *reinterpret_cast<const short8*>(&Bs[(wn + j*16 + l15)*64 + ks*32 + quad*8]);
            for(int i = 0; i < 4; i++)
                for(int j = 0; j < 4; j++)
                    acc[i][j] = __builtin_amdgcn_mfma_f32_16x16x32_bf16(af[i], bf[j], acc[i][j], 0, 0, 0);
        }
    }
    for(int i = 0; i < 4; i++)
        for(int j = 0; j < 4; j++)
            for(int r = 0; r < 4; r++){
                int m = tm + wm + i*16 + quad*4 + r;
                int n = tn + wn + j*16 + l15;
                out[(size_t)m*ND + n] = acc[i][j][r];
            }
}

// ---------------- launcher ----------------
extern "C" void kernel_launch(void* const* d_in, const int* in_sizes, int n_in,
                              void* d_out, int out_size, void* d_ws, size_t ws_size,
                              hipStream_t stream){
    const float* q    = (const float*)d_in[0];
    const float* k    = (const float*)d_in[1];
    const float* v    = (const float*)d_in[2];
    const float* mask = (const float*)d_in[3];
    const float* Wq   = (const float*)d_in[4];
    const float* Wk   = (const float*)d_in[5];
    const float* Wv   = (const float*)d_in[6];
    const float* Wo   = (const float*)d_in[7];
    char* ws = (char*)d_ws;
    float*          biasf = (float*)(ws + OFF_BIAS);
    unsigned*       bflag = (unsigned*)(ws + OFF_FLAG);
    unsigned short* wqp= (unsigned short*)(ws + OFF_WQ);
    unsigned short* wkp= (unsigned short*)(ws + OFF_WK);
    unsigned short* wvp= (unsigned short*)(ws + OFF_WV);
    unsigned short* wop= (unsigned short*)(ws + OFF_WO);
    unsigned short* qw = (unsigned short*)(ws + OFF_Q);
    unsigned short* kw = (unsigned short*)(ws + OFF_K);
    unsigned short* vw = (unsigned short*)(ws + OFF_V);
    unsigned short* ow = (unsigned short*)(ws + OFF_O);
    unsigned short* qb = (unsigned short*)(ws + OFF_QB);
    unsigned short* kb = (unsigned short*)(ws + OFF_O);   // dead before attn writes O
    unsigned short* vb = (unsigned short*)d_out;          // scratch; overwritten by gemm_out

    packw_kernel<<<dim3(144, 4), 256, 0, stream>>>(Wq, Wk, Wv, Wo, wqp, wkp, wvp, wop, bflag);
    bias_kernel<<<dim3(2048), 256, 0, stream>>>(mask, biasf, bflag);
    cast_kernel<<<dim3(3072, 3), 256, 0, stream>>>(q, k, v, qb, kb, vb);
    gemm_proj<<<dim3(64, 6, 2), 256, 0, stream>>>(qb, kb, wqp, wkp, qw, kw);
    gemm_projT<<<dim3(6, 64), 256, 0, stream>>>(wvp, vb, vw);
    attn3_kernel<<<dim3(16, 48), 256, 0, stream>>>(qw, kw, vw, biasf, bflag, ow);
    gemm_out<<<dim3(64, 6), 256, 0, stream>>>(ow, wop, (float*)d_out);
}

// Round 7
// 305.955 us; speedup vs baseline: 1.0631x; 1.0631x over previous
//
#include <hip/hip_runtime.h>
#include <hip/hip_bf16.h>

// MHA: B=4 S=2048 D=768 H=12 K=V=64, fp32 in/out, bf16 MFMA internally.
// R11: (1) GEMMs reverted to R9 reg-staged structure (measured 14us faster
// than R10's gload_lds+cast: these GEMMs are latency/balance-bound, not
// staging-VALU-bound). (2) gemm_projT/gemm_out re-tiled 128x64 -> 768
// blocks = 3/CU balanced (was 384 = 1.5/CU -> wall 2x T_block).
// (3) attn SMAX: v_cvt_pk_bf16_f32 (1 op) replaces software f2bf RNE
// (~5-6 ops x 32 vals/kt) + explicit no-bias branch drops the z+0.0f adds.
// attn otherwise R9: K dbuf[2]+V tribuf[3], 1 barrier/kt, QK->PV->SMAX.

typedef __attribute__((ext_vector_type(8))) short short8;
typedef __attribute__((ext_vector_type(4))) short s16x4;
typedef __attribute__((ext_vector_type(4))) float f32x4;
typedef __attribute__((ext_vector_type(16))) float f32x16;
typedef __attribute__((ext_vector_type(2))) int int2v;
typedef __attribute__((ext_vector_type(4))) int int4v;

#define NB 4
#define NS 2048
#define ND 768
#define NH 12
#define HD 64

#define QSCALE 0.18033688011112043f     /* 0.125 * log2(e): folded into Q */
#define NLOG2E (-1.4426950408889634e9f) /* -1e9 * log2(e)                 */

__device__ __forceinline__ unsigned short f2bf(float f){
    __hip_bfloat16 h = __float2bfloat16(f);
    return __builtin_bit_cast(unsigned short, h);
}

// HW packed f32->bf16 (RNE), 1 VALU op; no builtin on gfx950 -> inline asm
__device__ __forceinline__ unsigned cvtpk(float a, float b){
    unsigned r;
    asm("v_cvt_pk_bf16_f32 %0, %1, %2" : "=v"(r) : "v"(a), "v"(b));
    return r;
}

// ---------------- workspace layout (bytes) ----------------
#define OFF_BIAS ((size_t)0)          // fp32 [2048][2048] log2-domain bias (16.8 MB)
#define OFF_FLAG ((size_t)33554432)   // u32: 1 if any bias value nonzero
#define OFF_WQ  ((size_t)37748736)
#define OFF_WK  ((size_t)38928384)
#define OFF_WV  ((size_t)40108032)
#define OFF_WO  ((size_t)41287680)
#define OFF_Q   ((size_t)42467328)   // [B,H,S,64] bf16, pre-scaled by QSCALE
#define OFF_K   ((size_t)55050240)   // [B,H,S,64] bf16
#define OFF_V   ((size_t)67633152)   // [B,H,64,S] bf16 (V^T)
#define OFF_O   ((size_t)80216064)   // [B,H,S,64] == scrambled [B*S,768]

// ---------------- prep: bias[q][m] = (1-mask)*(-1e9)*log2e, fp32 --------
__global__ __launch_bounds__(256) void bias_kernel(
    const float* __restrict__ mask, float* __restrict__ biasf,
    unsigned* __restrict__ flag){
    size_t t = (size_t)blockIdx.x*256 + threadIdx.x;
    f32x4 a = reinterpret_cast<const f32x4*>(mask)[2*t];
    f32x4 b = reinterpret_cast<const f32x4*>(mask)[2*t+1];
    f32x4 oa, ob;
    bool nz = false;
    for(int i=0;i<4;i++){
        oa[i] = (1.0f-a[i])*NLOG2E; ob[i] = (1.0f-b[i])*NLOG2E;
        nz = nz || (oa[i] != 0.0f) || (ob[i] != 0.0f);
    }
    reinterpret_cast<f32x4*>(biasf)[2*t]   = oa;
    reinterpret_cast<f32x4*>(biasf)[2*t+1] = ob;
    if(nz) atomicOr(flag, 1u);
}

// ---------------- prep: tiled transpose-cast of weights ----------------
__global__ __launch_bounds__(256) void packw_kernel(
    const float* __restrict__ Wq, const float* __restrict__ Wk,
    const float* __restrict__ Wv, const float* __restrict__ Wo,
    unsigned short* __restrict__ wq, unsigned short* __restrict__ wk,
    unsigned short* __restrict__ wv, unsigned short* __restrict__ wo,
    unsigned* __restrict__ flag){
    if(blockIdx.x==0 && blockIdx.y==0 && threadIdx.x==0) *flag = 0u;
    int y = blockIdx.y, x = blockIdx.x;
    const float* src; unsigned short* dst; int sstr, r0, c0;
    if(y < 3){
        const float* W = y==0 ? Wq : (y==1 ? Wk : Wv);
        unsigned short* o = y==0 ? wq : (y==1 ? wk : wv);
        int h = x/12, dt = x%12;
        src = W + (size_t)h*ND*HD; sstr = HD; r0 = dt*64; c0 = 0;
        dst = o + (size_t)h*HD*ND;
    } else {
        src = Wo; sstr = ND; r0 = (x/12)*64; c0 = (x%12)*64;
        dst = wo;
    }
    __shared__ unsigned short T[64*68];
    int t = threadIdx.x;
    int tr = t>>4, tc4 = (t&15)*4;
    for(int it=0; it<4; it++){
        int r = it*16 + tr;
        f32x4 vv = *reinterpret_cast<const f32x4*>(src + (size_t)(r0+r)*sstr + c0 + tc4);
        s16x4 p; p[0]=(short)f2bf(vv[0]); p[1]=(short)f2bf(vv[1]);
                 p[2]=(short)f2bf(vv[2]); p[3]=(short)f2bf(vv[3]);
        *reinterpret_cast<s16x4*>(&T[r*68 + tc4]) = p;
    }
    __syncthreads();
    for(int it=0; it<4; it++){
        int c = it*16 + tr;
        s16x4 p;
        p[0] = (short)T[(tc4+0)*68 + c];
        p[1] = (short)T[(tc4+1)*68 + c];
        p[2] = (short)T[(tc4+2)*68 + c];
        p[3] = (short)T[(tc4+3)*68 + c];
        *reinterpret_cast<s16x4*>(dst + (size_t)(c0+c)*ND + r0 + tc4) = p;
    }
}

// ---------------- Q/K projections: C[128x128] = cast(X) * Wt^T ----------
#define LDP 72
#define CPT 136
__global__ __launch_bounds__(256) void gemm_proj(
    const float* __restrict__ qf, const float* __restrict__ kf,
    const unsigned short* __restrict__ wq, const unsigned short* __restrict__ wk,
    unsigned short* __restrict__ oq, unsigned short* __restrict__ ok){
    int z = blockIdx.z;
    const float* Af          = z==0 ? qf : kf;
    const unsigned short* Bt = z==0 ? wq : wk;
    unsigned short* dst      = z==0 ? oq : ok;
    const float qsc          = z==0 ? QSCALE : 1.0f;

    __shared__ alignas(16) unsigned short smem[2*128*LDP]; // 36864 B, aliased
    unsigned short* As = smem;
    unsigned short* Bs = smem + 128*LDP;
    int tid = threadIdx.x;
    int lane = tid & 63, wave = tid >> 6;
    int l15 = lane & 15, quad = lane >> 4;
    int wm = (wave >> 1)*64, wn = (wave & 1)*64;
    int tm = blockIdx.x*128, tn = blockIdx.y*128;

    f32x4 acc[4][4] = {};
    for(int k0 = 0; k0 < ND; k0 += 64){
        __syncthreads();
        for(int i = 0; i < 4; i++){
            int flat = i*256 + tid;
            int row = flat >> 3, cb = flat & 7;
            f32x4 a0 = *reinterpret_cast<const f32x4*>(Af + (size_t)(tm+row)*ND + k0 + cb*8);
            f32x4 a1 = *reinterpret_cast<const f32x4*>(Af + (size_t)(tm+row)*ND + k0 + cb*8 + 4);
            short8 av;
            av[0]=(short)f2bf(a0[0]); av[1]=(short)f2bf(a0[1]); av[2]=(short)f2bf(a0[2]); av[3]=(short)f2bf(a0[3]);
            av[4]=(short)f2bf(a1[0]); av[5]=(short)f2bf(a1[1]); av[6]=(short)f2bf(a1[2]); av[7]=(short)f2bf(a1[3]);
            *reinterpret_cast<short8*>(&As[row*LDP + cb*8]) = av;
            *reinterpret_cast<short8*>(&Bs[row*LDP + cb*8]) =
                *reinterpret_cast<const short8*>(Bt + (size_t)(tn+row)*ND + k0 + cb*8);
        }
        __syncthreads();
        for(int ks = 0; ks < 2; ks++){
            short8 af[4], bf[4];
            for(int i = 0; i < 4; i++)
                af[i] = *reinterpret_cast<const short8*>(&As[(wm + i*16 + l15)*LDP + ks*32 + quad*8]);
            for(int j = 0; j < 4; j++)
                bf[j] = *reinterpret_cast<const short8*>(&Bs[(wn + j*16 + l15)*LDP + ks*32 + quad*8]);
            for(int i = 0; i < 4; i++)
                for(int j = 0; j < 4; j++)
                    acc[i][j] = __builtin_amdgcn_mfma_f32_16x16x32_bf16(af[i], bf[j], acc[i][j], 0, 0, 0);
        }
    }
    __syncthreads();
    unsigned short* Cs = smem;   // [128][CPT]
    for(int i = 0; i < 4; i++)
        for(int j = 0; j < 4; j++)
            for(int r = 0; r < 4; r++)
                Cs[(wm + i*16 + quad*4 + r)*CPT + wn + j*16 + l15] = f2bf(acc[i][j][r]*qsc);
    __syncthreads();
    for(int c8 = 0; c8 < 8; c8++){
        int idx = c8*256 + tid;
        int row = idx >> 4, ch = idx & 15;
        short8 val = *reinterpret_cast<const short8*>(&Cs[row*CPT + ch*8]);
        int m = tm + row, n = tn + ch*8;
        int b = m >> 11, s = m & 2047, h = n >> 6, kk = n & 63;
        *reinterpret_cast<short8*>(dst + ((size_t)(b*NH + h)*NS + s)*HD + kk) = val;
    }
}

// ---------------- V^T projection: 128(m) x 64(n) tiles, 768 blocks ------
__global__ __launch_bounds__(256) void gemm_projT(
    const unsigned short* __restrict__ A,   // wv [768][768]  (rows = h*64+kk)
    const float* __restrict__ Bf,           // values [8192][768] fp32
    unsigned short* __restrict__ dst){      // vtws [48][64][2048]
    __shared__ alignas(16) unsigned short smem[(128+64)*LDP]; // 27648 B
    unsigned short* As = smem;              // [128][72]
    unsigned short* Bs = smem + 128*LDP;    // [64][72]
    int tid = threadIdx.x;
    int lane = tid & 63, wave = tid >> 6;
    int l15 = lane & 15, quad = lane >> 4;
    int wm = (wave >> 1)*64, wn = (wave & 1)*32;
    int tm = blockIdx.x*128, tn = blockIdx.y*64;

    f32x4 acc[4][2] = {};
    for(int k0 = 0; k0 < ND; k0 += 64){
        __syncthreads();
        #pragma unroll
        for(int i = 0; i < 4; i++){
            int flat = i*256 + tid;
            int row = flat >> 3, cb = flat & 7;
            *reinterpret_cast<short8*>(&As[row*LDP + cb*8]) =
                *reinterpret_cast<const short8*>(A + (size_t)(tm+row)*ND + k0 + cb*8);
        }
        #pragma unroll
        for(int i = 0; i < 2; i++){
            int flat = i*256 + tid;
            int row = flat >> 3, cb = flat & 7;
            f32x4 b0 = *reinterpret_cast<const f32x4*>(Bf + (size_t)(tn+row)*ND + k0 + cb*8);
            f32x4 b1 = *reinterpret_cast<const f32x4*>(Bf + (size_t)(tn+row)*ND + k0 + cb*8 + 4);
            short8 bv;
            bv[0]=(short)f2bf(b0[0]); bv[1]=(short)f2bf(b0[1]); bv[2]=(short)f2bf(b0[2]); bv[3]=(short)f2bf(b0[3]);
            bv[4]=(short)f2bf(b1[0]); bv[5]=(short)f2bf(b1[1]); bv[6]=(short)f2bf(b1[2]); bv[7]=(short)f2bf(b1[3]);
            *reinterpret_cast<short8*>(&Bs[row*LDP + cb*8]) = bv;
        }
        __syncthreads();
        for(int ks = 0; ks < 2; ks++){
            short8 af[4], bf[2];
            for(int i = 0; i < 4; i++)
                af[i] = *reinterpret_cast<const short8*>(&As[(wm + i*16 + l15)*LDP + ks*32 + quad*8]);
            for(int j = 0; j < 2; j++)
                bf[j] = *reinterpret_cast<const short8*>(&Bs[(wn + j*16 + l15)*LDP + ks*32 + quad*8]);
            for(int i = 0; i < 4; i++)
                for(int j = 0; j < 2; j++)
                    acc[i][j] = __builtin_amdgcn_mfma_f32_16x16x32_bf16(af[i], bf[j], acc[i][j], 0, 0, 0);
        }
    }
    __syncthreads();
    unsigned short* Cs = smem;   // [128][72]
    for(int i = 0; i < 4; i++)
        for(int j = 0; j < 2; j++)
            for(int r = 0; r < 4; r++)
                Cs[(wm + i*16 + quad*4 + r)*LDP + wn + j*16 + l15] = f2bf(acc[i][j][r]);
    __syncthreads();
    int b = tn >> 11, s0 = tn & 2047;
    for(int c4 = 0; c4 < 4; c4++){
        int idx = c4*256 + tid;
        int row = idx >> 3, ch = idx & 7;
        short8 val = *reinterpret_cast<const short8*>(&Cs[row*LDP + ch*8]);
        int h = (tm + row) >> 6, kk = (tm + row) & 63;
        *reinterpret_cast<short8*>(dst + ((size_t)(b*NH + h)*HD + kk)*NS + s0 + ch*8) = val;
    }
}

// ---------------- flash attention: 32x32 MFMA, in-reg softmax, pipelined --
// grid (16, 48): x = 128-row q-tile, y = b*H+h. 4 waves x 32 q-rows.
// Iter t: stage(t); barrier; QK(t) -> z2; PV(t-1); softmax(t) -> afragP.
__global__ __launch_bounds__(256, 3) void attn3_kernel(
    const unsigned short* __restrict__ qws, const unsigned short* __restrict__ kws,
    const unsigned short* __restrict__ vtws, const float* __restrict__ biasf,
    const unsigned* __restrict__ bflag, unsigned short* __restrict__ ows){
    const int bh = blockIdx.y, qt = blockIdx.x;
    const int tid = threadIdx.x, lane = tid & 63, wave = tid >> 6;
    const int l31 = lane & 31, hi = lane >> 5;

    __shared__ alignas(16) unsigned short Ks[2][64*72];   // 18432 B
    __shared__ alignas(16) unsigned short Vs[3][64*72];   // 27648 B (total 46080)

    const size_t bhq = (size_t)bh * NS;
    const int qb0 = qt*128 + wave*32;
    const bool hasBias = (*bflag != 0u);   // uniform

    short8 bq[4];
    #pragma unroll
    for(int ds=0; ds<4; ds++)
        bq[ds] = *reinterpret_cast<const short8*>(
            qws + (bhq + qb0 + l31)*HD + ds*16 + hi*8);

    const float* bp = biasf + (size_t)(qb0 + l31)*NS + hi*4;

    const int rS = tid >> 3;       // 0..31
    const int cS = tid & 7;        // 0..7

    short8 rk[2], rv[2];
    #define LOADK(i,KT) rk[i] = *reinterpret_cast<const short8*>(kws + (bhq + (size_t)(KT)*64 + (i)*32 + rS)*HD + cS*8)
    #define LOADV(i,KT) rv[i] = *reinterpret_cast<const short8*>(vtws + ((size_t)bh*HD + (i)*32 + rS)*NS + (size_t)(KT)*64 + cS*8)

    #define STAGE(KB, VB)                                                         \
    {                                                                             \
        _Pragma("unroll")                                                         \
        for(int i=0;i<2;i++){                                                     \
            int row = i*32 + rS;                                                  \
            *reinterpret_cast<short8*>(&Ks[KB][row*72 + cS*8]) = rk[i];           \
            *reinterpret_cast<short8*>(&Vs[VB][row*72 + cS*8]) = rv[i];           \
        }                                                                         \
    }

    #define QK(KB)                                                                \
    {                                                                             \
        _Pragma("unroll")                                                         \
        for(int kb=0; kb<2; kb++){                                                \
            f32x16 zt = {};                                                       \
            _Pragma("unroll")                                                     \
            for(int ds=0; ds<4; ds++){                                            \
                short8 ak = *reinterpret_cast<const short8*>(                     \
                    &Ks[KB][(kb*32 + l31)*72 + ds*16 + hi*8]);                    \
                zt = __builtin_amdgcn_mfma_f32_32x32x16_bf16(ak, bq[ds], zt, 0, 0, 0);\
            }                                                                     \
            z2[kb] = zt;                                                          \
        }                                                                         \
    }

    #define SMAX(KT)                                                              \
    {                                                                             \
        _Pragma("unroll")                                                         \
        for(int kb=0; kb<2; kb++){                                                \
            unsigned p[8];                                                        \
            if(hasBias){                                                          \
                _Pragma("unroll")                                                 \
                for(int g=0; g<4; g++){                                           \
                    f32x4 bb = *reinterpret_cast<const f32x4*>(bp + (KT)*64 + kb*32 + g*8);\
                    float e0 = exp2f(z2[kb][g*4+0] + bb[0]);                      \
                    float e1 = exp2f(z2[kb][g*4+1] + bb[1]);                      \
                    float e2 = exp2f(z2[kb][g*4+2] + bb[2]);                      \
                    float e3 = exp2f(z2[kb][g*4+3] + bb[3]);                      \
                    p[g*2+0] = cvtpk(e0, e1);                                     \
                    p[g*2+1] = cvtpk(e2, e3);                                     \
                }                                                                 \
            } else {                                                              \
                _Pragma("unroll")                                                 \
                for(int g=0; g<4; g++){                                           \
                    float e0 = exp2f(z2[kb][g*4+0]);                              \
                    float e1 = exp2f(z2[kb][g*4+1]);                              \
                    float e2 = exp2f(z2[kb][g*4+2]);                              \
                    float e3 = exp2f(z2[kb][g*4+3]);                              \
                    p[g*2+0] = cvtpk(e0, e1);                                     \
                    p[g*2+1] = cvtpk(e2, e3);                                     \
                }                                                                 \
            }                                                                     \
            int2v sA = __builtin_amdgcn_permlane32_swap((int)p[0], (int)p[2], false, false); \
            int2v sB = __builtin_amdgcn_permlane32_swap((int)p[1], (int)p[3], false, false); \
            int2v sC = __builtin_amdgcn_permlane32_swap((int)p[4], (int)p[6], false, false); \
            int2v sD = __builtin_amdgcn_permlane32_swap((int)p[5], (int)p[7], false, false); \
            int4v f0; f0[0]=sA[0]; f0[1]=sB[0]; f0[2]=sA[1]; f0[3]=sB[1];         \
            int4v f1; f1[0]=sC[0]; f1[1]=sD[0]; f1[2]=sC[1]; f1[3]=sD[1];         \
            afragP[kb*2+0] = __builtin_bit_cast(short8, f0);                      \
            afragP[kb*2+1] = __builtin_bit_cast(short8, f1);                      \
        }                                                                         \
    }

    #define PVACC(VB)                                                             \
    {                                                                             \
        _Pragma("unroll")                                                         \
        for(int kst=0; kst<4; kst++){                                             \
            zacc = __builtin_amdgcn_mfma_f32_32x32x16_bf16(afragP[kst], vone, zacc, 0, 0, 0); \
            _Pragma("unroll")                                                     \
            for(int nb=0; nb<2; nb++){                                            \
                short8 bv = *reinterpret_cast<const short8*>(                     \
                    &Vs[VB][(nb*32 + l31)*72 + kst*16 + hi*8]);                   \
                oacc[nb] = __builtin_amdgcn_mfma_f32_32x32x16_bf16(afragP[kst], bv, oacc[nb], 0, 0, 0); \
            }                                                                     \
        }                                                                         \
    }

    f32x16 oacc[2] = {};
    f32x16 zacc = {};
    f32x16 z2[2];
    short8 afragP[4];
    short8 vone;
    #pragma unroll
    for(int i=0;i<8;i++) vone[i] = (short)0x3F80;   // bf16 1.0

    LOADK(0,0); LOADK(1,0); LOADV(0,0); LOADV(1,0);
    STAGE(0, 0)
    __syncthreads();
    LOADK(0,1); LOADK(1,1); LOADV(0,1); LOADV(1,1);
    __builtin_amdgcn_s_setprio(1);
    QK(0)
    __builtin_amdgcn_s_setprio(0);
    SMAX(0)

    for(int kt = 1; kt < 32; kt++){
        const int cb = kt & 1;
        const int vb = kt % 3;
        const int vp = (kt-1) % 3;
        STAGE(cb, vb)
        __syncthreads();
        int ktn = kt < 31 ? kt+1 : 31;
        LOADK(0,ktn); LOADK(1,ktn); LOADV(0,ktn); LOADV(1,ktn);

        __builtin_amdgcn_s_setprio(1);
        QK(cb)
        PVACC(vp)
        __builtin_amdgcn_s_setprio(0);
        SMAX(kt)
    }
    {
        const int vp = 31 % 3;   // = 1
        __builtin_amdgcn_s_setprio(1);
        PVACC(vp)
        __builtin_amdgcn_s_setprio(0);
    }

    float inv[16];
    #pragma unroll
    for(int r=0;r<16;r++) inv[r] = 1.0f / zacc[r];
    #pragma unroll
    for(int nb=0;nb<2;nb++)
        #pragma unroll
        for(int r=0;r<16;r++){
            int q = qb0 + (r&3) + 8*(r>>2) + 4*hi;
            ows[(bhq + q)*HD + nb*32 + l31] = f2bf(oacc[nb][r]*inv[r]);
        }
    #undef LOADK
    #undef LOADV
    #undef STAGE
    #undef QK
    #undef SMAX
    #undef PVACC
}

// ---------------- output projection: 128(m) x 64(n) tiles, 768 blocks ----
__global__ __launch_bounds__(256) void gemm_out(
    const unsigned short* __restrict__ A, const unsigned short* __restrict__ Bt,
    float* __restrict__ out){
    __shared__ alignas(16) unsigned short smem[(128+64)*LDP]; // 27648 B
    unsigned short* As = smem;              // [128][72]
    unsigned short* Bs = smem + 128*LDP;    // [64][72]
    int tid = threadIdx.x;
    int lane = tid & 63, wave = tid >> 6;
    int l15 = lane & 15, quad = lane >> 4;
    int wm = (wave >> 1)*64, wn = (wave & 1)*32;
    int tm = blockIdx.x*128, tn = blockIdx.y*64;

    f32x4 acc[4][2] = {};
    for(int k0 = 0; k0 < ND; k0 += 64){
        __syncthreads();
        #pragma unroll
        for(int i = 0; i < 4; i++){
            int flat = i*256 + tid;
            int row = flat >> 3, cb = flat & 7;
            *reinterpret_cast<short8*>(&As[row*LDP + cb*8]) =
                *reinterpret_cast<const short8*>(A  + (size_t)(tm+row)*ND + k0 + cb*8);
        }
        #pragma unroll
        for(int i = 0; i < 2; i++){
            int flat = i*256 + tid;
            int row = flat >> 3, cb = flat & 7;
            *reinterpret_cast<short8*>(&Bs[row*LDP + cb*8]) =
                *reinterpret_cast<const short8*>(Bt + (size_t)(tn+row)*ND + k0 + cb*8);
        }
        __syncthreads();
        for(int ks = 0; ks < 2; ks++){
            short8 af[4], bf[2];
            for(int i = 0; i < 4; i++)
                af[i] = *reinterpret_cast<const short8*>(&As[(wm + i*16 + l15)*LDP + ks*32 + quad*8]);
            for(int j = 0; j < 2; j++)
                bf[j] = *reinterpret_cast<const short8*>(&Bs[(wn + j*16 + l15)*LDP + ks*32 + quad*8]);
            for(int i = 0; i < 4; i++)
                for(int j = 0; j < 2; j++)
                    acc[i][j] = __builtin_amdgcn_mfma_f32_16x16x32_bf16(af[i], bf[j], acc[i][j], 0, 0, 0);
        }
    }
    for(int i = 0; i < 4; i++)
        for(int j = 0; j < 2; j++)
            for(int r = 0; r < 4; r++){
                int m = tm + wm + i*16 + quad*4 + r;
                int n = tn + wn + j*16 + l15;
                out[(size_t)m*ND + n] = acc[i][j][r];
            }
}

// ---------------- launcher ----------------
extern "C" void kernel_launch(void* const* d_in, const int* in_sizes, int n_in,
                              void* d_out, int out_size, void* d_ws, size_t ws_size,
                              hipStream_t stream){
    const float* q    = (const float*)d_in[0];
    const float* k    = (const float*)d_in[1];
    const float* v    = (const float*)d_in[2];
    const float* mask = (const float*)d_in[3];
    const float* Wq   = (const float*)d_in[4];
    const float* Wk   = (const float*)d_in[5];
    const float* Wv   = (const float*)d_in[6];
    const float* Wo   = (const float*)d_in[7];
    char* ws = (char*)d_ws;
    float*          biasf = (float*)(ws + OFF_BIAS);
    unsigned*       bflag = (unsigned*)(ws + OFF_FLAG);
    unsigned short* wqp= (unsigned short*)(ws + OFF_WQ);
    unsigned short* wkp= (unsigned short*)(ws + OFF_WK);
    unsigned short* wvp= (unsigned short*)(ws + OFF_WV);
    unsigned short* wop= (unsigned short*)(ws + OFF_WO);
    unsigned short* qw = (unsigned short*)(ws + OFF_Q);
    unsigned short* kw = (unsigned short*)(ws + OFF_K);
    unsigned short* vw = (unsigned short*)(ws + OFF_V);
    unsigned short* ow = (unsigned short*)(ws + OFF_O);

    packw_kernel<<<dim3(144, 4), 256, 0, stream>>>(Wq, Wk, Wv, Wo, wqp, wkp, wvp, wop, bflag);
    bias_kernel<<<dim3(2048), 256, 0, stream>>>(mask, biasf, bflag);
    gemm_proj<<<dim3(64, 6, 2), 256, 0, stream>>>(q, k, wqp, wkp, qw, kw);
    gemm_projT<<<dim3(6, 128), 256, 0, stream>>>(wvp, v, vw);
    attn3_kernel<<<dim3(16, 48), 256, 0, stream>>>(qw, kw, vw, biasf, bflag, ow);
    gemm_out<<<dim3(64, 12), 256, 0, stream>>>(ow, wop, (float*)d_out);
}

// Round 8
// 284.139 us; speedup vs baseline: 1.1448x; 1.0768x over previous
//
#include <hip/hip_runtime.h>
#include <hip/hip_bf16.h>

// MHA: B=4 S=2048 D=768 H=12 K=V=64, fp32 in/out, bf16 MFMA internally.
// R12:
//  (1) gemm_fused: Q-proj, K-proj, V-projT in ONE dispatch, grid (64,6,3).
//      Removes 2 stream-serialization gaps + overlaps straggler tails
//      (balance is global across 1152 blocks). projT back to its R9
//      128x128 tiling as fused zone z=2.
//  (2) Staging fp32->bf16 via v_cvt_pk_bf16_f32 (pack8: 4 ops) instead of
//      8 scalar f2bf. RNE == __float2bfloat16 (R7 evidence: bit-identical).
//  (3) attn: exp2f -> bare v_exp_f32 (asm). OCML exp2 carries a denormal
//      guard (~5 instrs); attn is VALU-issue-bound (VALUBusy 60 + Mfma 31
//      = 91%), so the wrapper cut should show. Masked -1.4e9 -> 0 either way.
//  attn otherwise R11: K dbuf[2]+V tribuf[3], 1 barrier/kt, QK->PV->SMAX,
//  cvtpk+permlane32_swap in-register softmax, no-bias fast path.

typedef __attribute__((ext_vector_type(8))) short short8;
typedef __attribute__((ext_vector_type(4))) short s16x4;
typedef __attribute__((ext_vector_type(4))) float f32x4;
typedef __attribute__((ext_vector_type(16))) float f32x16;
typedef __attribute__((ext_vector_type(2))) int int2v;
typedef __attribute__((ext_vector_type(4))) int int4v;

#define NB 4
#define NS 2048
#define ND 768
#define NH 12
#define HD 64

#define QSCALE 0.18033688011112043f     /* 0.125 * log2(e): folded into Q */
#define NLOG2E (-1.4426950408889634e9f) /* -1e9 * log2(e)                 */

__device__ __forceinline__ unsigned short f2bf(float f){
    __hip_bfloat16 h = __float2bfloat16(f);
    return __builtin_bit_cast(unsigned short, h);
}

// HW packed f32->bf16 (RNE), 1 VALU op
__device__ __forceinline__ unsigned cvtpk(float a, float b){
    unsigned r;
    asm("v_cvt_pk_bf16_f32 %0, %1, %2" : "=v"(r) : "v"(a), "v"(b));
    return r;
}

// bare v_exp_f32: D = 2^S0 (no OCML denormal guard)
__device__ __forceinline__ float fexp2(float x){
    float r;
    asm("v_exp_f32 %0, %1" : "=v"(r) : "v"(x));
    return r;
}

// pack 8 fp32 -> short8 of bf16 via 4 cvtpk
__device__ __forceinline__ short8 pack8(f32x4 a, f32x4 b){
    int4v r;
    r[0] = (int)cvtpk(a[0], a[1]);
    r[1] = (int)cvtpk(a[2], a[3]);
    r[2] = (int)cvtpk(b[0], b[1]);
    r[3] = (int)cvtpk(b[2], b[3]);
    return __builtin_bit_cast(short8, r);
}

// ---------------- workspace layout (bytes) ----------------
#define OFF_BIAS ((size_t)0)          // fp32 [2048][2048] log2-domain bias (16.8 MB)
#define OFF_FLAG ((size_t)33554432)   // u32: 1 if any bias value nonzero
#define OFF_WQ  ((size_t)37748736)
#define OFF_WK  ((size_t)38928384)
#define OFF_WV  ((size_t)40108032)
#define OFF_WO  ((size_t)41287680)
#define OFF_Q   ((size_t)42467328)   // [B,H,S,64] bf16, pre-scaled by QSCALE
#define OFF_K   ((size_t)55050240)   // [B,H,S,64] bf16
#define OFF_V   ((size_t)67633152)   // [B,H,64,S] bf16 (V^T)
#define OFF_O   ((size_t)80216064)   // [B,H,S,64] == scrambled [B*S,768]

// ---------------- prep: bias[q][m] = (1-mask)*(-1e9)*log2e, fp32 --------
__global__ __launch_bounds__(256) void bias_kernel(
    const float* __restrict__ mask, float* __restrict__ biasf,
    unsigned* __restrict__ flag){
    size_t t = (size_t)blockIdx.x*256 + threadIdx.x;
    f32x4 a = reinterpret_cast<const f32x4*>(mask)[2*t];
    f32x4 b = reinterpret_cast<const f32x4*>(mask)[2*t+1];
    f32x4 oa, ob;
    bool nz = false;
    for(int i=0;i<4;i++){
        oa[i] = (1.0f-a[i])*NLOG2E; ob[i] = (1.0f-b[i])*NLOG2E;
        nz = nz || (oa[i] != 0.0f) || (ob[i] != 0.0f);
    }
    reinterpret_cast<f32x4*>(biasf)[2*t]   = oa;
    reinterpret_cast<f32x4*>(biasf)[2*t+1] = ob;
    if(nz) atomicOr(flag, 1u);
}

// ---------------- prep: tiled transpose-cast of weights ----------------
__global__ __launch_bounds__(256) void packw_kernel(
    const float* __restrict__ Wq, const float* __restrict__ Wk,
    const float* __restrict__ Wv, const float* __restrict__ Wo,
    unsigned short* __restrict__ wq, unsigned short* __restrict__ wk,
    unsigned short* __restrict__ wv, unsigned short* __restrict__ wo,
    unsigned* __restrict__ flag){
    if(blockIdx.x==0 && blockIdx.y==0 && threadIdx.x==0) *flag = 0u;
    int y = blockIdx.y, x = blockIdx.x;
    const float* src; unsigned short* dst; int sstr, r0, c0;
    if(y < 3){
        const float* W = y==0 ? Wq : (y==1 ? Wk : Wv);
        unsigned short* o = y==0 ? wq : (y==1 ? wk : wv);
        int h = x/12, dt = x%12;
        src = W + (size_t)h*ND*HD; sstr = HD; r0 = dt*64; c0 = 0;
        dst = o + (size_t)h*HD*ND;
    } else {
        src = Wo; sstr = ND; r0 = (x/12)*64; c0 = (x%12)*64;
        dst = wo;
    }
    __shared__ unsigned short T[64*68];
    int t = threadIdx.x;
    int tr = t>>4, tc4 = (t&15)*4;
    for(int it=0; it<4; it++){
        int r = it*16 + tr;
        f32x4 vv = *reinterpret_cast<const f32x4*>(src + (size_t)(r0+r)*sstr + c0 + tc4);
        s16x4 p; p[0]=(short)f2bf(vv[0]); p[1]=(short)f2bf(vv[1]);
                 p[2]=(short)f2bf(vv[2]); p[3]=(short)f2bf(vv[3]);
        *reinterpret_cast<s16x4*>(&T[r*68 + tc4]) = p;
    }
    __syncthreads();
    for(int it=0; it<4; it++){
        int c = it*16 + tr;
        s16x4 p;
        p[0] = (short)T[(tc4+0)*68 + c];
        p[1] = (short)T[(tc4+1)*68 + c];
        p[2] = (short)T[(tc4+2)*68 + c];
        p[3] = (short)T[(tc4+3)*68 + c];
        *reinterpret_cast<s16x4*>(dst + (size_t)(c0+c)*ND + r0 + tc4) = p;
    }
}

// ---------------- fused projections: z=0 Qproj, z=1 Kproj, z=2 V^Tproj --
#define LDP 72
#define CPT 136
__global__ __launch_bounds__(256) void gemm_fused(
    const float* __restrict__ qf, const float* __restrict__ kf,
    const float* __restrict__ vf,
    const unsigned short* __restrict__ wq, const unsigned short* __restrict__ wk,
    const unsigned short* __restrict__ wv,
    unsigned short* __restrict__ oq, unsigned short* __restrict__ ok,
    unsigned short* __restrict__ ov){
    const int z = blockIdx.z;
    __shared__ alignas(16) unsigned short smem[2*128*LDP]; // 36864 B, aliased
    unsigned short* As = smem;
    unsigned short* Bs = smem + 128*LDP;
    int tid = threadIdx.x;
    int lane = tid & 63, wave = tid >> 6;
    int l15 = lane & 15, quad = lane >> 4;
    int wm = (wave >> 1)*64, wn = (wave & 1)*64;

    if(z < 2){
        // -------- Q/K projection: C[128x128] = cast(X) * Wt^T --------
        const float* Af          = z==0 ? qf : kf;
        const unsigned short* Bt = z==0 ? wq : wk;
        unsigned short* dst      = z==0 ? oq : ok;
        const float qsc          = z==0 ? QSCALE : 1.0f;
        int tm = blockIdx.x*128, tn = blockIdx.y*128;

        f32x4 acc[4][4] = {};
        for(int k0 = 0; k0 < ND; k0 += 64){
            __syncthreads();
            for(int i = 0; i < 4; i++){
                int flat = i*256 + tid;
                int row = flat >> 3, cb = flat & 7;
                f32x4 a0 = *reinterpret_cast<const f32x4*>(Af + (size_t)(tm+row)*ND + k0 + cb*8);
                f32x4 a1 = *reinterpret_cast<const f32x4*>(Af + (size_t)(tm+row)*ND + k0 + cb*8 + 4);
                *reinterpret_cast<short8*>(&As[row*LDP + cb*8]) = pack8(a0, a1);
                *reinterpret_cast<short8*>(&Bs[row*LDP + cb*8]) =
                    *reinterpret_cast<const short8*>(Bt + (size_t)(tn+row)*ND + k0 + cb*8);
            }
            __syncthreads();
            for(int ks = 0; ks < 2; ks++){
                short8 af[4], bf[4];
                for(int i = 0; i < 4; i++)
                    af[i] = *reinterpret_cast<const short8*>(&As[(wm + i*16 + l15)*LDP + ks*32 + quad*8]);
                for(int j = 0; j < 4; j++)
                    bf[j] = *reinterpret_cast<const short8*>(&Bs[(wn + j*16 + l15)*LDP + ks*32 + quad*8]);
                for(int i = 0; i < 4; i++)
                    for(int j = 0; j < 4; j++)
                        acc[i][j] = __builtin_amdgcn_mfma_f32_16x16x32_bf16(af[i], bf[j], acc[i][j], 0, 0, 0);
            }
        }
        __syncthreads();
        unsigned short* Cs = smem;   // [128][CPT]
        for(int i = 0; i < 4; i++)
            for(int j = 0; j < 4; j++)
                for(int r = 0; r < 4; r++)
                    Cs[(wm + i*16 + quad*4 + r)*CPT + wn + j*16 + l15] = f2bf(acc[i][j][r]*qsc);
        __syncthreads();
        for(int c8 = 0; c8 < 8; c8++){
            int idx = c8*256 + tid;
            int row = idx >> 4, ch = idx & 15;
            short8 val = *reinterpret_cast<const short8*>(&Cs[row*CPT + ch*8]);
            int m = tm + row, n = tn + ch*8;
            int b = m >> 11, s = m & 2047, h = n >> 6, kk = n & 63;
            *reinterpret_cast<short8*>(dst + ((size_t)(b*NH + h)*NS + s)*HD + kk) = val;
        }
    } else {
        // -------- V^T projection (operand-swapped): A=wv bf16, B=values f32
        int tm = blockIdx.y*128;   // 0..5  (wv rows h*64+kk)
        int tn = blockIdx.x*128;   // 0..63 (B*S rows)

        f32x4 acc[4][4] = {};
        for(int k0 = 0; k0 < ND; k0 += 64){
            __syncthreads();
            for(int i = 0; i < 4; i++){
                int flat = i*256 + tid;
                int row = flat >> 3, cb = flat & 7;
                *reinterpret_cast<short8*>(&As[row*LDP + cb*8]) =
                    *reinterpret_cast<const short8*>(wv + (size_t)(tm+row)*ND + k0 + cb*8);
                f32x4 b0 = *reinterpret_cast<const f32x4*>(vf + (size_t)(tn+row)*ND + k0 + cb*8);
                f32x4 b1 = *reinterpret_cast<const f32x4*>(vf + (size_t)(tn+row)*ND + k0 + cb*8 + 4);
                *reinterpret_cast<short8*>(&Bs[row*LDP + cb*8]) = pack8(b0, b1);
            }
            __syncthreads();
            for(int ks = 0; ks < 2; ks++){
                short8 af[4], bf[4];
                for(int i = 0; i < 4; i++)
                    af[i] = *reinterpret_cast<const short8*>(&As[(wm + i*16 + l15)*LDP + ks*32 + quad*8]);
                for(int j = 0; j < 4; j++)
                    bf[j] = *reinterpret_cast<const short8*>(&Bs[(wn + j*16 + l15)*LDP + ks*32 + quad*8]);
                for(int i = 0; i < 4; i++)
                    for(int j = 0; j < 4; j++)
                        acc[i][j] = __builtin_amdgcn_mfma_f32_16x16x32_bf16(af[i], bf[j], acc[i][j], 0, 0, 0);
            }
        }
        __syncthreads();
        unsigned short* Cs = smem;   // [128 rows=m][CPT cols=n]
        for(int i = 0; i < 4; i++)
            for(int j = 0; j < 4; j++)
                for(int r = 0; r < 4; r++)
                    Cs[(wm + i*16 + quad*4 + r)*CPT + wn + j*16 + l15] = f2bf(acc[i][j][r]);
        __syncthreads();
        int b = tn >> 11, s0 = tn & 2047;
        for(int c8 = 0; c8 < 8; c8++){
            int idx = c8*256 + tid;
            int row = idx >> 4, ch = idx & 15;
            short8 val = *reinterpret_cast<const short8*>(&Cs[row*CPT + ch*8]);
            int h = (tm + row) >> 6, kk = (tm + row) & 63;
            *reinterpret_cast<short8*>(ov + ((size_t)(b*NH + h)*HD + kk)*NS + s0 + ch*8) = val;
        }
    }
}

// ---------------- flash attention: 32x32 MFMA, in-reg softmax, pipelined --
// grid (16, 48): x = 128-row q-tile, y = b*H+h. 4 waves x 32 q-rows.
// Iter t: stage(t); barrier; QK(t) -> z2; PV(t-1); softmax(t) -> afragP.
__global__ __launch_bounds__(256, 3) void attn3_kernel(
    const unsigned short* __restrict__ qws, const unsigned short* __restrict__ kws,
    const unsigned short* __restrict__ vtws, const float* __restrict__ biasf,
    const unsigned* __restrict__ bflag, unsigned short* __restrict__ ows){
    const int bh = blockIdx.y, qt = blockIdx.x;
    const int tid = threadIdx.x, lane = tid & 63, wave = tid >> 6;
    const int l31 = lane & 31, hi = lane >> 5;

    __shared__ alignas(16) unsigned short Ks[2][64*72];   // 18432 B
    __shared__ alignas(16) unsigned short Vs[3][64*72];   // 27648 B (total 46080)

    const size_t bhq = (size_t)bh * NS;
    const int qb0 = qt*128 + wave*32;
    const bool hasBias = (*bflag != 0u);   // uniform

    short8 bq[4];
    #pragma unroll
    for(int ds=0; ds<4; ds++)
        bq[ds] = *reinterpret_cast<const short8*>(
            qws + (bhq + qb0 + l31)*HD + ds*16 + hi*8);

    const float* bp = biasf + (size_t)(qb0 + l31)*NS + hi*4;

    const int rS = tid >> 3;       // 0..31
    const int cS = tid & 7;        // 0..7

    short8 rk[2], rv[2];
    #define LOADK(i,KT) rk[i] = *reinterpret_cast<const short8*>(kws + (bhq + (size_t)(KT)*64 + (i)*32 + rS)*HD + cS*8)
    #define LOADV(i,KT) rv[i] = *reinterpret_cast<const short8*>(vtws + ((size_t)bh*HD + (i)*32 + rS)*NS + (size_t)(KT)*64 + cS*8)

    #define STAGE(KB, VB)                                                         \
    {                                                                             \
        _Pragma("unroll")                                                         \
        for(int i=0;i<2;i++){                                                     \
            int row = i*32 + rS;                                                  \
            *reinterpret_cast<short8*>(&Ks[KB][row*72 + cS*8]) = rk[i];           \
            *reinterpret_cast<short8*>(&Vs[VB][row*72 + cS*8]) = rv[i];           \
        }                                                                         \
    }

    #define QK(KB)                                                                \
    {                                                                             \
        _Pragma("unroll")                                                         \
        for(int kb=0; kb<2; kb++){                                                \
            f32x16 zt = {};                                                       \
            _Pragma("unroll")                                                     \
            for(int ds=0; ds<4; ds++){                                            \
                short8 ak = *reinterpret_cast<const short8*>(                     \
                    &Ks[KB][(kb*32 + l31)*72 + ds*16 + hi*8]);                    \
                zt = __builtin_amdgcn_mfma_f32_32x32x16_bf16(ak, bq[ds], zt, 0, 0, 0);\
            }                                                                     \
            z2[kb] = zt;                                                          \
        }                                                                         \
    }

    #define SMAX(KT)                                                              \
    {                                                                             \
        _Pragma("unroll")                                                         \
        for(int kb=0; kb<2; kb++){                                                \
            unsigned p[8];                                                        \
            if(hasBias){                                                          \
                _Pragma("unroll")                                                 \
                for(int g=0; g<4; g++){                                           \
                    f32x4 bb = *reinterpret_cast<const f32x4*>(bp + (KT)*64 + kb*32 + g*8);\
                    float e0 = fexp2(z2[kb][g*4+0] + bb[0]);                      \
                    float e1 = fexp2(z2[kb][g*4+1] + bb[1]);                      \
                    float e2 = fexp2(z2[kb][g*4+2] + bb[2]);                      \
                    float e3 = fexp2(z2[kb][g*4+3] + bb[3]);                      \
                    p[g*2+0] = cvtpk(e0, e1);                                     \
                    p[g*2+1] = cvtpk(e2, e3);                                     \
                }                                                                 \
            } else {                                                              \
                _Pragma("unroll")                                                 \
                for(int g=0; g<4; g++){                                           \
                    float e0 = fexp2(z2[kb][g*4+0]);                              \
                    float e1 = fexp2(z2[kb][g*4+1]);                              \
                    float e2 = fexp2(z2[kb][g*4+2]);                              \
                    float e3 = fexp2(z2[kb][g*4+3]);                              \
                    p[g*2+0] = cvtpk(e0, e1);                                     \
                    p[g*2+1] = cvtpk(e2, e3);                                     \
                }                                                                 \
            }                                                                     \
            int2v sA = __builtin_amdgcn_permlane32_swap((int)p[0], (int)p[2], false, false); \
            int2v sB = __builtin_amdgcn_permlane32_swap((int)p[1], (int)p[3], false, false); \
            int2v sC = __builtin_amdgcn_permlane32_swap((int)p[4], (int)p[6], false, false); \
            int2v sD = __builtin_amdgcn_permlane32_swap((int)p[5], (int)p[7], false, false); \
            int4v f0; f0[0]=sA[0]; f0[1]=sB[0]; f0[2]=sA[1]; f0[3]=sB[1];         \
            int4v f1; f1[0]=sC[0]; f1[1]=sD[0]; f1[2]=sC[1]; f1[3]=sD[1];         \
            afragP[kb*2+0] = __builtin_bit_cast(short8, f0);                      \
            afragP[kb*2+1] = __builtin_bit_cast(short8, f1);                      \
        }                                                                         \
    }

    #define PVACC(VB)                                                             \
    {                                                                             \
        _Pragma("unroll")                                                         \
        for(int kst=0; kst<4; kst++){                                             \
            zacc = __builtin_amdgcn_mfma_f32_32x32x16_bf16(afragP[kst], vone, zacc, 0, 0, 0); \
            _Pragma("unroll")                                                     \
            for(int nb=0; nb<2; nb++){                                            \
                short8 bv = *reinterpret_cast<const short8*>(                     \
                    &Vs[VB][(nb*32 + l31)*72 + kst*16 + hi*8]);                   \
                oacc[nb] = __builtin_amdgcn_mfma_f32_32x32x16_bf16(afragP[kst], bv, oacc[nb], 0, 0, 0); \
            }                                                                     \
        }                                                                         \
    }

    f32x16 oacc[2] = {};
    f32x16 zacc = {};
    f32x16 z2[2];
    short8 afragP[4];
    short8 vone;
    #pragma unroll
    for(int i=0;i<8;i++) vone[i] = (short)0x3F80;   // bf16 1.0

    LOADK(0,0); LOADK(1,0); LOADV(0,0); LOADV(1,0);
    STAGE(0, 0)
    __syncthreads();
    LOADK(0,1); LOADK(1,1); LOADV(0,1); LOADV(1,1);
    __builtin_amdgcn_s_setprio(1);
    QK(0)
    __builtin_amdgcn_s_setprio(0);
    SMAX(0)

    for(int kt = 1; kt < 32; kt++){
        const int cb = kt & 1;
        const int vb = kt % 3;
        const int vp = (kt-1) % 3;
        STAGE(cb, vb)
        __syncthreads();
        int ktn = kt < 31 ? kt+1 : 31;
        LOADK(0,ktn); LOADK(1,ktn); LOADV(0,ktn); LOADV(1,ktn);

        __builtin_amdgcn_s_setprio(1);
        QK(cb)
        PVACC(vp)
        __builtin_amdgcn_s_setprio(0);
        SMAX(kt)
    }
    {
        const int vp = 31 % 3;   // = 1
        __builtin_amdgcn_s_setprio(1);
        PVACC(vp)
        __builtin_amdgcn_s_setprio(0);
    }

    float inv[16];
    #pragma unroll
    for(int r=0;r<16;r++) inv[r] = 1.0f / zacc[r];
    #pragma unroll
    for(int nb=0;nb<2;nb++)
        #pragma unroll
        for(int r=0;r<16;r++){
            int q = qb0 + (r&3) + 8*(r>>2) + 4*hi;
            ows[(bhq + q)*HD + nb*32 + l31] = f2bf(oacc[nb][r]*inv[r]);
        }
    #undef LOADK
    #undef LOADV
    #undef STAGE
    #undef QK
    #undef SMAX
    #undef PVACC
}

// ---------------- output projection: 128(m) x 64(n) tiles, 768 blocks ----
__global__ __launch_bounds__(256) void gemm_out(
    const unsigned short* __restrict__ A, const unsigned short* __restrict__ Bt,
    float* __restrict__ out){
    __shared__ alignas(16) unsigned short smem[(128+64)*LDP]; // 27648 B
    unsigned short* As = smem;              // [128][72]
    unsigned short* Bs = smem + 128*LDP;    // [64][72]
    int tid = threadIdx.x;
    int lane = tid & 63, wave = tid >> 6;
    int l15 = lane & 15, quad = lane >> 4;
    int wm = (wave >> 1)*64, wn = (wave & 1)*32;
    int tm = blockIdx.x*128, tn = blockIdx.y*64;

    f32x4 acc[4][2] = {};
    for(int k0 = 0; k0 < ND; k0 += 64){
        __syncthreads();
        #pragma unroll
        for(int i = 0; i < 4; i++){
            int flat = i*256 + tid;
            int row = flat >> 3, cb = flat & 7;
            *reinterpret_cast<short8*>(&As[row*LDP + cb*8]) =
                *reinterpret_cast<const short8*>(A  + (size_t)(tm+row)*ND + k0 + cb*8);
        }
        #pragma unroll
        for(int i = 0; i < 2; i++){
            int flat = i*256 + tid;
            int row = flat >> 3, cb = flat & 7;
            *reinterpret_cast<short8*>(&Bs[row*LDP + cb*8]) =
                *reinterpret_cast<const short8*>(Bt + (size_t)(tn+row)*ND + k0 + cb*8);
        }
        __syncthreads();
        for(int ks = 0; ks < 2; ks++){
            short8 af[4], bf[2];
            for(int i = 0; i < 4; i++)
                af[i] = *reinterpret_cast<const short8*>(&As[(wm + i*16 + l15)*LDP + ks*32 + quad*8]);
            for(int j = 0; j < 2; j++)
                bf[j] = *reinterpret_cast<const short8*>(&Bs[(wn + j*16 + l15)*LDP + ks*32 + quad*8]);
            for(int i = 0; i < 4; i++)
                for(int j = 0; j < 2; j++)
                    acc[i][j] = __builtin_amdgcn_mfma_f32_16x16x32_bf16(af[i], bf[j], acc[i][j], 0, 0, 0);
        }
    }
    for(int i = 0; i < 4; i++)
        for(int j = 0; j < 2; j++)
            for(int r = 0; r < 4; r++){
                int m = tm + wm + i*16 + quad*4 + r;
                int n = tn + wn + j*16 + l15;
                out[(size_t)m*ND + n] = acc[i][j][r];
            }
}

// ---------------- launcher ----------------
extern "C" void kernel_launch(void* const* d_in, const int* in_sizes, int n_in,
                              void* d_out, int out_size, void* d_ws, size_t ws_size,
                              hipStream_t stream){
    const float* q    = (const float*)d_in[0];
    const float* k    = (const float*)d_in[1];
    const float* v    = (const float*)d_in[2];
    const float* mask = (const float*)d_in[3];
    const float* Wq   = (const float*)d_in[4];
    const float* Wk   = (const float*)d_in[5];
    const float* Wv   = (const float*)d_in[6];
    const float* Wo   = (const float*)d_in[7];
    char* ws = (char*)d_ws;
    float*          biasf = (float*)(ws + OFF_BIAS);
    unsigned*       bflag = (unsigned*)(ws + OFF_FLAG);
    unsigned short* wqp= (unsigned short*)(ws + OFF_WQ);
    unsigned short* wkp= (unsigned short*)(ws + OFF_WK);
    unsigned short* wvp= (unsigned short*)(ws + OFF_WV);
    unsigned short* wop= (unsigned short*)(ws + OFF_WO);
    unsigned short* qw = (unsigned short*)(ws + OFF_Q);
    unsigned short* kw = (unsigned short*)(ws + OFF_K);
    unsigned short* vw = (unsigned short*)(ws + OFF_V);
    unsigned short* ow = (unsigned short*)(ws + OFF_O);

    packw_kernel<<<dim3(144, 4), 256, 0, stream>>>(Wq, Wk, Wv, Wo, wqp, wkp, wvp, wop, bflag);
    bias_kernel<<<dim3(2048), 256, 0, stream>>>(mask, biasf, bflag);
    gemm_fused<<<dim3(64, 6, 3), 256, 0, stream>>>(q, k, v, wqp, wkp, wvp, qw, kw, vw);
    attn3_kernel<<<dim3(16, 48), 256, 0, stream>>>(qw, kw, vw, biasf, bflag, ow);
    gemm_out<<<dim3(64, 12), 256, 0, stream>>>(ow, wop, (float*)d_out);
}

// Round 9
// 268.571 us; speedup vs baseline: 1.2111x; 1.0580x over previous
//
#include <hip/hip_runtime.h>
#include <hip/hip_bf16.h>

// MHA: B=4 S=2048 D=768 H=12 K=V=64, fp32 in/out, bf16 MFMA internally.
// R13: GEMM latency attack (T14 register-prefetch pipeline).
//  gemm_fused counters (R12): MfmaUtil 14 / VALU 19 / HBM 17% / Occ 17 —
//  latency-bound; each of 12 K-steps exposed a full HBM round-trip because
//  staging loads were consumed by ds_write immediately. Now: loads for
//  tile t+1 issue into VGPRs BEFORE MFMA(t); regs->LDS write happens after
//  the post-MFMA barrier. Load latency hides under MFMA issue. Applied to
//  both gemm_fused zones and gemm_out. attn3 unchanged from R12.
// Numerics: identical arithmetic/rounding -> absmax unchanged.

typedef __attribute__((ext_vector_type(8))) short short8;
typedef __attribute__((ext_vector_type(4))) short s16x4;
typedef __attribute__((ext_vector_type(4))) float f32x4;
typedef __attribute__((ext_vector_type(16))) float f32x16;
typedef __attribute__((ext_vector_type(2))) int int2v;
typedef __attribute__((ext_vector_type(4))) int int4v;

#define NB 4
#define NS 2048
#define ND 768
#define NH 12
#define HD 64

#define QSCALE 0.18033688011112043f     /* 0.125 * log2(e): folded into Q */
#define NLOG2E (-1.4426950408889634e9f) /* -1e9 * log2(e)                 */

__device__ __forceinline__ unsigned short f2bf(float f){
    __hip_bfloat16 h = __float2bfloat16(f);
    return __builtin_bit_cast(unsigned short, h);
}

// HW packed f32->bf16 (RNE), 1 VALU op
__device__ __forceinline__ unsigned cvtpk(float a, float b){
    unsigned r;
    asm("v_cvt_pk_bf16_f32 %0, %1, %2" : "=v"(r) : "v"(a), "v"(b));
    return r;
}

// bare v_exp_f32: D = 2^S0 (no OCML denormal guard)
__device__ __forceinline__ float fexp2(float x){
    float r;
    asm("v_exp_f32 %0, %1" : "=v"(r) : "v"(x));
    return r;
}

// pack 8 fp32 -> short8 of bf16 via 4 cvtpk
__device__ __forceinline__ short8 pack8(f32x4 a, f32x4 b){
    int4v r;
    r[0] = (int)cvtpk(a[0], a[1]);
    r[1] = (int)cvtpk(a[2], a[3]);
    r[2] = (int)cvtpk(b[0], b[1]);
    r[3] = (int)cvtpk(b[2], b[3]);
    return __builtin_bit_cast(short8, r);
}

// ---------------- workspace layout (bytes) ----------------
#define OFF_BIAS ((size_t)0)          // fp32 [2048][2048] log2-domain bias (16.8 MB)
#define OFF_FLAG ((size_t)33554432)   // u32: 1 if any bias value nonzero
#define OFF_WQ  ((size_t)37748736)
#define OFF_WK  ((size_t)38928384)
#define OFF_WV  ((size_t)40108032)
#define OFF_WO  ((size_t)41287680)
#define OFF_Q   ((size_t)42467328)   // [B,H,S,64] bf16, pre-scaled by QSCALE
#define OFF_K   ((size_t)55050240)   // [B,H,S,64] bf16
#define OFF_V   ((size_t)67633152)   // [B,H,64,S] bf16 (V^T)
#define OFF_O   ((size_t)80216064)   // [B,H,S,64] == scrambled [B*S,768]

// ---------------- prep: bias[q][m] = (1-mask)*(-1e9)*log2e, fp32 --------
__global__ __launch_bounds__(256) void bias_kernel(
    const float* __restrict__ mask, float* __restrict__ biasf,
    unsigned* __restrict__ flag){
    size_t t = (size_t)blockIdx.x*256 + threadIdx.x;
    f32x4 a = reinterpret_cast<const f32x4*>(mask)[2*t];
    f32x4 b = reinterpret_cast<const f32x4*>(mask)[2*t+1];
    f32x4 oa, ob;
    bool nz = false;
    for(int i=0;i<4;i++){
        oa[i] = (1.0f-a[i])*NLOG2E; ob[i] = (1.0f-b[i])*NLOG2E;
        nz = nz || (oa[i] != 0.0f) || (ob[i] != 0.0f);
    }
    reinterpret_cast<f32x4*>(biasf)[2*t]   = oa;
    reinterpret_cast<f32x4*>(biasf)[2*t+1] = ob;
    if(nz) atomicOr(flag, 1u);
}

// ---------------- prep: tiled transpose-cast of weights ----------------
__global__ __launch_bounds__(256) void packw_kernel(
    const float* __restrict__ Wq, const float* __restrict__ Wk,
    const float* __restrict__ Wv, const float* __restrict__ Wo,
    unsigned short* __restrict__ wq, unsigned short* __restrict__ wk,
    unsigned short* __restrict__ wv, unsigned short* __restrict__ wo,
    unsigned* __restrict__ flag){
    if(blockIdx.x==0 && blockIdx.y==0 && threadIdx.x==0) *flag = 0u;
    int y = blockIdx.y, x = blockIdx.x;
    const float* src; unsigned short* dst; int sstr, r0, c0;
    if(y < 3){
        const float* W = y==0 ? Wq : (y==1 ? Wk : Wv);
        unsigned short* o = y==0 ? wq : (y==1 ? wk : wv);
        int h = x/12, dt = x%12;
        src = W + (size_t)h*ND*HD; sstr = HD; r0 = dt*64; c0 = 0;
        dst = o + (size_t)h*HD*ND;
    } else {
        src = Wo; sstr = ND; r0 = (x/12)*64; c0 = (x%12)*64;
        dst = wo;
    }
    __shared__ unsigned short T[64*68];
    int t = threadIdx.x;
    int tr = t>>4, tc4 = (t&15)*4;
    for(int it=0; it<4; it++){
        int r = it*16 + tr;
        f32x4 vv = *reinterpret_cast<const f32x4*>(src + (size_t)(r0+r)*sstr + c0 + tc4);
        s16x4 p; p[0]=(short)f2bf(vv[0]); p[1]=(short)f2bf(vv[1]);
                 p[2]=(short)f2bf(vv[2]); p[3]=(short)f2bf(vv[3]);
        *reinterpret_cast<s16x4*>(&T[r*68 + tc4]) = p;
    }
    __syncthreads();
    for(int it=0; it<4; it++){
        int c = it*16 + tr;
        s16x4 p;
        p[0] = (short)T[(tc4+0)*68 + c];
        p[1] = (short)T[(tc4+1)*68 + c];
        p[2] = (short)T[(tc4+2)*68 + c];
        p[3] = (short)T[(tc4+3)*68 + c];
        *reinterpret_cast<s16x4*>(dst + (size_t)(c0+c)*ND + r0 + tc4) = p;
    }
}

// ---------------- fused projections: z=0 Qproj, z=1 Kproj, z=2 V^Tproj --
// Register-prefetch pipeline: LOAD(t+1) issues before MFMA(t); regs->LDS
// after the post-MFMA barrier.
#define LDP 72
#define CPT 136
__global__ __launch_bounds__(256) void gemm_fused(
    const float* __restrict__ qf, const float* __restrict__ kf,
    const float* __restrict__ vf,
    const unsigned short* __restrict__ wq, const unsigned short* __restrict__ wk,
    const unsigned short* __restrict__ wv,
    unsigned short* __restrict__ oq, unsigned short* __restrict__ ok,
    unsigned short* __restrict__ ov){
    const int z = blockIdx.z;
    __shared__ alignas(16) unsigned short smem[2*128*LDP]; // 36864 B, aliased
    unsigned short* As = smem;
    unsigned short* Bs = smem + 128*LDP;
    int tid = threadIdx.x;
    int lane = tid & 63, wave = tid >> 6;
    int l15 = lane & 15, quad = lane >> 4;
    int wm = (wave >> 1)*64, wn = (wave & 1)*64;
    const int srow = tid >> 3, scb = tid & 7;   // staging row/col-block

    if(z < 2){
        // -------- Q/K projection: C[128x128] = cast(X) * Wt^T --------
        const float* Af          = z==0 ? qf : kf;
        const unsigned short* Bt = z==0 ? wq : wk;
        unsigned short* dst      = z==0 ? oq : ok;
        const float qsc          = z==0 ? QSCALE : 1.0f;
        int tm = blockIdx.x*128, tn = blockIdx.y*128;

        f32x4 ra0[4], ra1[4]; short8 rb[4];
        #define LOADQK(KK)                                                        \
        {   int k0 = (KK)*64;                                                     \
            _Pragma("unroll")                                                     \
            for(int i=0;i<4;i++){                                                 \
                int row = i*32 + srow;                                            \
                ra0[i] = *reinterpret_cast<const f32x4*>(Af + (size_t)(tm+row)*ND + k0 + scb*8);     \
                ra1[i] = *reinterpret_cast<const f32x4*>(Af + (size_t)(tm+row)*ND + k0 + scb*8 + 4); \
                rb[i]  = *reinterpret_cast<const short8*>(Bt + (size_t)(tn+row)*ND + k0 + scb*8);    \
            }                                                                     \
        }
        #define STOREQK                                                           \
        {   _Pragma("unroll")                                                     \
            for(int i=0;i<4;i++){                                                 \
                int row = i*32 + srow;                                            \
                *reinterpret_cast<short8*>(&As[row*LDP + scb*8]) = pack8(ra0[i], ra1[i]); \
                *reinterpret_cast<short8*>(&Bs[row*LDP + scb*8]) = rb[i];         \
            }                                                                     \
        }

        f32x4 acc[4][4] = {};
        LOADQK(0)
        STOREQK
        __syncthreads();
        LOADQK(1)
        for(int kk = 0; kk < 12; kk++){
            for(int ks = 0; ks < 2; ks++){
                short8 af[4], bf[4];
                for(int i = 0; i < 4; i++)
                    af[i] = *reinterpret_cast<const short8*>(&As[(wm + i*16 + l15)*LDP + ks*32 + quad*8]);
                for(int j = 0; j < 4; j++)
                    bf[j] = *reinterpret_cast<const short8*>(&Bs[(wn + j*16 + l15)*LDP + ks*32 + quad*8]);
                for(int i = 0; i < 4; i++)
                    for(int j = 0; j < 4; j++)
                        acc[i][j] = __builtin_amdgcn_mfma_f32_16x16x32_bf16(af[i], bf[j], acc[i][j], 0, 0, 0);
            }
            if(kk < 11){
                __syncthreads();      // readers done
                STOREQK               // tile kk+1 -> LDS
                __syncthreads();      // visible
                if(kk + 2 <= 11) LOADQK(kk+2)
            }
        }
        __syncthreads();
        unsigned short* Cs = smem;   // [128][CPT]
        for(int i = 0; i < 4; i++)
            for(int j = 0; j < 4; j++)
                for(int r = 0; r < 4; r++)
                    Cs[(wm + i*16 + quad*4 + r)*CPT + wn + j*16 + l15] = f2bf(acc[i][j][r]*qsc);
        __syncthreads();
        for(int c8 = 0; c8 < 8; c8++){
            int idx = c8*256 + tid;
            int row = idx >> 4, ch = idx & 15;
            short8 val = *reinterpret_cast<const short8*>(&Cs[row*CPT + ch*8]);
            int m = tm + row, n = tn + ch*8;
            int b = m >> 11, s = m & 2047, h = n >> 6, kk2 = n & 63;
            *reinterpret_cast<short8*>(dst + ((size_t)(b*NH + h)*NS + s)*HD + kk2) = val;
        }
        #undef LOADQK
        #undef STOREQK
    } else {
        // -------- V^T projection (operand-swapped): A=wv bf16, B=values f32
        int tm = blockIdx.y*128;   // 0..5  (wv rows h*64+kk)
        int tn = blockIdx.x*128;   // 0..63 (B*S rows)

        short8 rawv[4]; f32x4 rb0[4], rb1[4];
        #define LOADVT(KK)                                                        \
        {   int k0 = (KK)*64;                                                     \
            _Pragma("unroll")                                                     \
            for(int i=0;i<4;i++){                                                 \
                int row = i*32 + srow;                                            \
                rawv[i] = *reinterpret_cast<const short8*>(wv + (size_t)(tm+row)*ND + k0 + scb*8);  \
                rb0[i] = *reinterpret_cast<const f32x4*>(vf + (size_t)(tn+row)*ND + k0 + scb*8);    \
                rb1[i] = *reinterpret_cast<const f32x4*>(vf + (size_t)(tn+row)*ND + k0 + scb*8 + 4);\
            }                                                                     \
        }
        #define STOREVT                                                           \
        {   _Pragma("unroll")                                                     \
            for(int i=0;i<4;i++){                                                 \
                int row = i*32 + srow;                                            \
                *reinterpret_cast<short8*>(&As[row*LDP + scb*8]) = rawv[i];       \
                *reinterpret_cast<short8*>(&Bs[row*LDP + scb*8]) = pack8(rb0[i], rb1[i]); \
            }                                                                     \
        }

        f32x4 acc[4][4] = {};
        LOADVT(0)
        STOREVT
        __syncthreads();
        LOADVT(1)
        for(int kk = 0; kk < 12; kk++){
            for(int ks = 0; ks < 2; ks++){
                short8 af[4], bf[4];
                for(int i = 0; i < 4; i++)
                    af[i] = *reinterpret_cast<const short8*>(&As[(wm + i*16 + l15)*LDP + ks*32 + quad*8]);
                for(int j = 0; j < 4; j++)
                    bf[j] = *reinterpret_cast<const short8*>(&Bs[(wn + j*16 + l15)*LDP + ks*32 + quad*8]);
                for(int i = 0; i < 4; i++)
                    for(int j = 0; j < 4; j++)
                        acc[i][j] = __builtin_amdgcn_mfma_f32_16x16x32_bf16(af[i], bf[j], acc[i][j], 0, 0, 0);
            }
            if(kk < 11){
                __syncthreads();
                STOREVT
                __syncthreads();
                if(kk + 2 <= 11) LOADVT(kk+2)
            }
        }
        __syncthreads();
        unsigned short* Cs = smem;   // [128 rows=m][CPT cols=n]
        for(int i = 0; i < 4; i++)
            for(int j = 0; j < 4; j++)
                for(int r = 0; r < 4; r++)
                    Cs[(wm + i*16 + quad*4 + r)*CPT + wn + j*16 + l15] = f2bf(acc[i][j][r]);
        __syncthreads();
        int b = tn >> 11, s0 = tn & 2047;
        for(int c8 = 0; c8 < 8; c8++){
            int idx = c8*256 + tid;
            int row = idx >> 4, ch = idx & 15;
            short8 val = *reinterpret_cast<const short8*>(&Cs[row*CPT + ch*8]);
            int h = (tm + row) >> 6, kk2 = (tm + row) & 63;
            *reinterpret_cast<short8*>(ov + ((size_t)(b*NH + h)*HD + kk2)*NS + s0 + ch*8) = val;
        }
        #undef LOADVT
        #undef STOREVT
    }
}

// ---------------- flash attention: 32x32 MFMA, in-reg softmax, pipelined --
// grid (16, 48): x = 128-row q-tile, y = b*H+h. 4 waves x 32 q-rows.
// Iter t: stage(t); barrier; QK(t) -> z2; PV(t-1); softmax(t) -> afragP.
__global__ __launch_bounds__(256, 3) void attn3_kernel(
    const unsigned short* __restrict__ qws, const unsigned short* __restrict__ kws,
    const unsigned short* __restrict__ vtws, const float* __restrict__ biasf,
    const unsigned* __restrict__ bflag, unsigned short* __restrict__ ows){
    const int bh = blockIdx.y, qt = blockIdx.x;
    const int tid = threadIdx.x, lane = tid & 63, wave = tid >> 6;
    const int l31 = lane & 31, hi = lane >> 5;

    __shared__ alignas(16) unsigned short Ks[2][64*72];   // 18432 B
    __shared__ alignas(16) unsigned short Vs[3][64*72];   // 27648 B (total 46080)

    const size_t bhq = (size_t)bh * NS;
    const int qb0 = qt*128 + wave*32;
    const bool hasBias = (*bflag != 0u);   // uniform

    short8 bq[4];
    #pragma unroll
    for(int ds=0; ds<4; ds++)
        bq[ds] = *reinterpret_cast<const short8*>(
            qws + (bhq + qb0 + l31)*HD + ds*16 + hi*8);

    const float* bp = biasf + (size_t)(qb0 + l31)*NS + hi*4;

    const int rS = tid >> 3;       // 0..31
    const int cS = tid & 7;        // 0..7

    short8 rk[2], rv[2];
    #define LOADK(i,KT) rk[i] = *reinterpret_cast<const short8*>(kws + (bhq + (size_t)(KT)*64 + (i)*32 + rS)*HD + cS*8)
    #define LOADV(i,KT) rv[i] = *reinterpret_cast<const short8*>(vtws + ((size_t)bh*HD + (i)*32 + rS)*NS + (size_t)(KT)*64 + cS*8)

    #define STAGE(KB, VB)                                                         \
    {                                                                             \
        _Pragma("unroll")                                                         \
        for(int i=0;i<2;i++){                                                     \
            int row = i*32 + rS;                                                  \
            *reinterpret_cast<short8*>(&Ks[KB][row*72 + cS*8]) = rk[i];           \
            *reinterpret_cast<short8*>(&Vs[VB][row*72 + cS*8]) = rv[i];           \
        }                                                                         \
    }

    #define QK(KB)                                                                \
    {                                                                             \
        _Pragma("unroll")                                                         \
        for(int kb=0; kb<2; kb++){                                                \
            f32x16 zt = {};                                                       \
            _Pragma("unroll")                                                     \
            for(int ds=0; ds<4; ds++){                                            \
                short8 ak = *reinterpret_cast<const short8*>(                     \
                    &Ks[KB][(kb*32 + l31)*72 + ds*16 + hi*8]);                    \
                zt = __builtin_amdgcn_mfma_f32_32x32x16_bf16(ak, bq[ds], zt, 0, 0, 0);\
            }                                                                     \
            z2[kb] = zt;                                                          \
        }                                                                         \
    }

    #define SMAX(KT)                                                              \
    {                                                                             \
        _Pragma("unroll")                                                         \
        for(int kb=0; kb<2; kb++){                                                \
            unsigned p[8];                                                        \
            if(hasBias){                                                          \
                _Pragma("unroll")                                                 \
                for(int g=0; g<4; g++){                                           \
                    f32x4 bb = *reinterpret_cast<const f32x4*>(bp + (KT)*64 + kb*32 + g*8);\
                    float e0 = fexp2(z2[kb][g*4+0] + bb[0]);                      \
                    float e1 = fexp2(z2[kb][g*4+1] + bb[1]);                      \
                    float e2 = fexp2(z2[kb][g*4+2] + bb[2]);                      \
                    float e3 = fexp2(z2[kb][g*4+3] + bb[3]);                      \
                    p[g*2+0] = cvtpk(e0, e1);                                     \
                    p[g*2+1] = cvtpk(e2, e3);                                     \
                }                                                                 \
            } else {                                                              \
                _Pragma("unroll")                                                 \
                for(int g=0; g<4; g++){                                           \
                    float e0 = fexp2(z2[kb][g*4+0]);                              \
                    float e1 = fexp2(z2[kb][g*4+1]);                              \
                    float e2 = fexp2(z2[kb][g*4+2]);                              \
                    float e3 = fexp2(z2[kb][g*4+3]);                              \
                    p[g*2+0] = cvtpk(e0, e1);                                     \
                    p[g*2+1] = cvtpk(e2, e3);                                     \
                }                                                                 \
            }                                                                     \
            int2v sA = __builtin_amdgcn_permlane32_swap((int)p[0], (int)p[2], false, false); \
            int2v sB = __builtin_amdgcn_permlane32_swap((int)p[1], (int)p[3], false, false); \
            int2v sC = __builtin_amdgcn_permlane32_swap((int)p[4], (int)p[6], false, false); \
            int2v sD = __builtin_amdgcn_permlane32_swap((int)p[5], (int)p[7], false, false); \
            int4v f0; f0[0]=sA[0]; f0[1]=sB[0]; f0[2]=sA[1]; f0[3]=sB[1];         \
            int4v f1; f1[0]=sC[0]; f1[1]=sD[0]; f1[2]=sC[1]; f1[3]=sD[1];         \
            afragP[kb*2+0] = __builtin_bit_cast(short8, f0);                      \
            afragP[kb*2+1] = __builtin_bit_cast(short8, f1);                      \
        }                                                                         \
    }

    #define PVACC(VB)                                                             \
    {                                                                             \
        _Pragma("unroll")                                                         \
        for(int kst=0; kst<4; kst++){                                             \
            zacc = __builtin_amdgcn_mfma_f32_32x32x16_bf16(afragP[kst], vone, zacc, 0, 0, 0); \
            _Pragma("unroll")                                                     \
            for(int nb=0; nb<2; nb++){                                            \
                short8 bv = *reinterpret_cast<const short8*>(                     \
                    &Vs[VB][(nb*32 + l31)*72 + kst*16 + hi*8]);                   \
                oacc[nb] = __builtin_amdgcn_mfma_f32_32x32x16_bf16(afragP[kst], bv, oacc[nb], 0, 0, 0); \
            }                                                                     \
        }                                                                         \
    }

    f32x16 oacc[2] = {};
    f32x16 zacc = {};
    f32x16 z2[2];
    short8 afragP[4];
    short8 vone;
    #pragma unroll
    for(int i=0;i<8;i++) vone[i] = (short)0x3F80;   // bf16 1.0

    LOADK(0,0); LOADK(1,0); LOADV(0,0); LOADV(1,0);
    STAGE(0, 0)
    __syncthreads();
    LOADK(0,1); LOADK(1,1); LOADV(0,1); LOADV(1,1);
    __builtin_amdgcn_s_setprio(1);
    QK(0)
    __builtin_amdgcn_s_setprio(0);
    SMAX(0)

    for(int kt = 1; kt < 32; kt++){
        const int cb = kt & 1;
        const int vb = kt % 3;
        const int vp = (kt-1) % 3;
        STAGE(cb, vb)
        __syncthreads();
        int ktn = kt < 31 ? kt+1 : 31;
        LOADK(0,ktn); LOADK(1,ktn); LOADV(0,ktn); LOADV(1,ktn);

        __builtin_amdgcn_s_setprio(1);
        QK(cb)
        PVACC(vp)
        __builtin_amdgcn_s_setprio(0);
        SMAX(kt)
    }
    {
        const int vp = 31 % 3;   // = 1
        __builtin_amdgcn_s_setprio(1);
        PVACC(vp)
        __builtin_amdgcn_s_setprio(0);
    }

    float inv[16];
    #pragma unroll
    for(int r=0;r<16;r++) inv[r] = 1.0f / zacc[r];
    #pragma unroll
    for(int nb=0;nb<2;nb++)
        #pragma unroll
        for(int r=0;r<16;r++){
            int q = qb0 + (r&3) + 8*(r>>2) + 4*hi;
            ows[(bhq + q)*HD + nb*32 + l31] = f2bf(oacc[nb][r]*inv[r]);
        }
    #undef LOADK
    #undef LOADV
    #undef STAGE
    #undef QK
    #undef SMAX
    #undef PVACC
}

// ---------------- output projection: 128(m) x 64(n) tiles, 768 blocks ----
// Register-prefetch pipeline (same as gemm_fused).
__global__ __launch_bounds__(256) void gemm_out(
    const unsigned short* __restrict__ A, const unsigned short* __restrict__ Bt,
    float* __restrict__ out){
    __shared__ alignas(16) unsigned short smem[(128+64)*LDP]; // 27648 B
    unsigned short* As = smem;              // [128][72]
    unsigned short* Bs = smem + 128*LDP;    // [64][72]
    int tid = threadIdx.x;
    int lane = tid & 63, wave = tid >> 6;
    int l15 = lane & 15, quad = lane >> 4;
    int wm = (wave >> 1)*64, wn = (wave & 1)*32;
    int tm = blockIdx.x*128, tn = blockIdx.y*64;
    const int srow = tid >> 3, scb = tid & 7;

    short8 rA[4], rB[2];
    #define LOADO(KK)                                                             \
    {   int k0 = (KK)*64;                                                         \
        _Pragma("unroll")                                                         \
        for(int i=0;i<4;i++)                                                      \
            rA[i] = *reinterpret_cast<const short8*>(A + (size_t)(tm + i*32 + srow)*ND + k0 + scb*8); \
        _Pragma("unroll")                                                         \
        for(int i=0;i<2;i++)                                                      \
            rB[i] = *reinterpret_cast<const short8*>(Bt + (size_t)(tn + i*32 + srow)*ND + k0 + scb*8);\
    }
    #define STOREO                                                                \
    {   _Pragma("unroll")                                                         \
        for(int i=0;i<4;i++)                                                      \
            *reinterpret_cast<short8*>(&As[(i*32 + srow)*LDP + scb*8]) = rA[i];   \
        _Pragma("unroll")                                                         \
        for(int i=0;i<2;i++)                                                      \
            *reinterpret_cast<short8*>(&Bs[(i*32 + srow)*LDP + scb*8]) = rB[i];   \
    }

    f32x4 acc[4][2] = {};
    LOADO(0)
    STOREO
    __syncthreads();
    LOADO(1)
    for(int kk = 0; kk < 12; kk++){
        for(int ks = 0; ks < 2; ks++){
            short8 af[4], bf[2];
            for(int i = 0; i < 4; i++)
                af[i] = *reinterpret_cast<const short8*>(&As[(wm + i*16 + l15)*LDP + ks*32 + quad*8]);
            for(int j = 0; j < 2; j++)
                bf[j] = *reinterpret_cast<const short8*>(&Bs[(wn + j*16 + l15)*LDP + ks*32 + quad*8]);
            for(int i = 0; i < 4; i++)
                for(int j = 0; j < 2; j++)
                    acc[i][j] = __builtin_amdgcn_mfma_f32_16x16x32_bf16(af[i], bf[j], acc[i][j], 0, 0, 0);
        }
        if(kk < 11){
            __syncthreads();
            STOREO
            __syncthreads();
            if(kk + 2 <= 11) LOADO(kk+2)
        }
    }
    for(int i = 0; i < 4; i++)
        for(int j = 0; j < 2; j++)
            for(int r = 0; r < 4; r++){
                int m = tm + wm + i*16 + quad*4 + r;
                int n = tn + wn + j*16 + l15;
                out[(size_t)m*ND + n] = acc[i][j][r];
            }
    #undef LOADO
    #undef STOREO
}

// ---------------- launcher ----------------
extern "C" void kernel_launch(void* const* d_in, const int* in_sizes, int n_in,
                              void* d_out, int out_size, void* d_ws, size_t ws_size,
                              hipStream_t stream){
    const float* q    = (const float*)d_in[0];
    const float* k    = (const float*)d_in[1];
    const float* v    = (const float*)d_in[2];
    const float* mask = (const float*)d_in[3];
    const float* Wq   = (const float*)d_in[4];
    const float* Wk   = (const float*)d_in[5];
    const float* Wv   = (const float*)d_in[6];
    const float* Wo   = (const float*)d_in[7];
    char* ws = (char*)d_ws;
    float*          biasf = (float*)(ws + OFF_BIAS);
    unsigned*       bflag = (unsigned*)(ws + OFF_FLAG);
    unsigned short* wqp= (unsigned short*)(ws + OFF_WQ);
    unsigned short* wkp= (unsigned short*)(ws + OFF_WK);
    unsigned short* wvp= (unsigned short*)(ws + OFF_WV);
    unsigned short* wop= (unsigned short*)(ws + OFF_WO);
    unsigned short* qw = (unsigned short*)(ws + OFF_Q);
    unsigned short* kw = (unsigned short*)(ws + OFF_K);
    unsigned short* vw = (unsigned short*)(ws + OFF_V);
    unsigned short* ow = (unsigned short*)(ws + OFF_O);

    packw_kernel<<<dim3(144, 4), 256, 0, stream>>>(Wq, Wk, Wv, Wo, wqp, wkp, wvp, wop, bflag);
    bias_kernel<<<dim3(2048), 256, 0, stream>>>(mask, biasf, bflag);
    gemm_fused<<<dim3(64, 6, 3), 256, 0, stream>>>(q, k, v, wqp, wkp, wvp, qw, kw, vw);
    attn3_kernel<<<dim3(16, 48), 256, 0, stream>>>(qw, kw, vw, biasf, bflag, ow);
    gemm_out<<<dim3(64, 12), 256, 0, stream>>>(ow, wop, (float*)d_out);
}

// Round 12
// 263.128 us; speedup vs baseline: 1.2362x; 1.0207x over previous
//
#include <hip/hip_runtime.h>
#include <hip/hip_bf16.h>

// MHA: B=4 S=2048 D=768 H=12 K=V=64, fp32 in/out, bf16 MFMA internally.
// R16: R13 (last passing, 268.6us) + bias-array elimination ONLY, in its
// safest form. R14's z=3-fold failed "container twice" in two rounds; the
// novelty is isolated out:
//  - flag_kernel: tiny scan, flag |= any(mask != 1.0f)  (== any bias != 0,
//    since (1-m)*NLOG2E = 0 iff m = 1). Replaces bias_kernel: 16.8MB read
//    + 4B write vs 33.6MB r/w. biasf array gone.
//  - attn3 hasBias path computes fmaf(1-m, NLOG2E, z) from mask directly
//    (dead for this benchmark: flag=0 -> fast path, numerics unchanged).
//  Carries R13: reg-prefetch GEMM pipeline, fexp2/cvtpk attn softmax,
//  K dbuf[2]+V tribuf[3] attn, 1 barrier/kt, 3-zone gemm_fused.

typedef __attribute__((ext_vector_type(8))) short short8;
typedef __attribute__((ext_vector_type(4))) short s16x4;
typedef __attribute__((ext_vector_type(4))) float f32x4;
typedef __attribute__((ext_vector_type(16))) float f32x16;
typedef __attribute__((ext_vector_type(2))) int int2v;
typedef __attribute__((ext_vector_type(4))) int int4v;

#define NB 4
#define NS 2048
#define ND 768
#define NH 12
#define HD 64

#define QSCALE 0.18033688011112043f     /* 0.125 * log2(e): folded into Q */
#define NLOG2E (-1.4426950408889634e9f) /* -1e9 * log2(e)                 */

__device__ __forceinline__ unsigned short f2bf(float f){
    __hip_bfloat16 h = __float2bfloat16(f);
    return __builtin_bit_cast(unsigned short, h);
}

// HW packed f32->bf16 (RNE), 1 VALU op
__device__ __forceinline__ unsigned cvtpk(float a, float b){
    unsigned r;
    asm("v_cvt_pk_bf16_f32 %0, %1, %2" : "=v"(r) : "v"(a), "v"(b));
    return r;
}

// bare v_exp_f32: D = 2^S0 (no OCML denormal guard)
__device__ __forceinline__ float fexp2(float x){
    float r;
    asm("v_exp_f32 %0, %1" : "=v"(r) : "v"(x));
    return r;
}

// pack 8 fp32 -> short8 of bf16 via 4 cvtpk
__device__ __forceinline__ short8 pack8(f32x4 a, f32x4 b){
    int4v r;
    r[0] = (int)cvtpk(a[0], a[1]);
    r[1] = (int)cvtpk(a[2], a[3]);
    r[2] = (int)cvtpk(b[0], b[1]);
    r[3] = (int)cvtpk(b[2], b[3]);
    return __builtin_bit_cast(short8, r);
}

// ---------------- workspace layout (bytes) ----------------
#define OFF_FLAG ((size_t)33554432)   // u32: 1 if any mask value != 1.0f
#define OFF_WQ  ((size_t)37748736)
#define OFF_WK  ((size_t)38928384)
#define OFF_WV  ((size_t)40108032)
#define OFF_WO  ((size_t)41287680)
#define OFF_Q   ((size_t)42467328)   // [B,H,S,64] bf16, pre-scaled by QSCALE
#define OFF_K   ((size_t)55050240)   // [B,H,S,64] bf16
#define OFF_V   ((size_t)67633152)   // [B,H,64,S] bf16 (V^T)
#define OFF_O   ((size_t)80216064)   // [B,H,S,64] == scrambled [B*S,768]

// ---------------- prep: flag |= any(mask != 1.0f) ----------------
__global__ __launch_bounds__(256) void flag_kernel(
    const float* __restrict__ mask, unsigned* __restrict__ flag){
    size_t base = (size_t)blockIdx.x*256 + threadIdx.x;
    bool nz = false;
    for(size_t i = base; i < (size_t)NS*NS/8; i += (size_t)gridDim.x*256){
        f32x4 a = reinterpret_cast<const f32x4*>(mask)[2*i];
        f32x4 b = reinterpret_cast<const f32x4*>(mask)[2*i+1];
        #pragma unroll
        for(int j=0;j<4;j++) nz = nz || (a[j] != 1.0f) || (b[j] != 1.0f);
    }
    if(nz) atomicOr(flag, 1u);
}

// ---------------- prep: tiled transpose-cast of weights ----------------
__global__ __launch_bounds__(256) void packw_kernel(
    const float* __restrict__ Wq, const float* __restrict__ Wk,
    const float* __restrict__ Wv, const float* __restrict__ Wo,
    unsigned short* __restrict__ wq, unsigned short* __restrict__ wk,
    unsigned short* __restrict__ wv, unsigned short* __restrict__ wo,
    unsigned* __restrict__ flag){
    if(blockIdx.x==0 && blockIdx.y==0 && threadIdx.x==0) *flag = 0u;
    int y = blockIdx.y, x = blockIdx.x;
    const float* src; unsigned short* dst; int sstr, r0, c0;
    if(y < 3){
        const float* W = y==0 ? Wq : (y==1 ? Wk : Wv);
        unsigned short* o = y==0 ? wq : (y==1 ? wk : wv);
        int h = x/12, dt = x%12;
        src = W + (size_t)h*ND*HD; sstr = HD; r0 = dt*64; c0 = 0;
        dst = o + (size_t)h*HD*ND;
    } else {
        src = Wo; sstr = ND; r0 = (x/12)*64; c0 = (x%12)*64;
        dst = wo;
    }
    __shared__ unsigned short T[64*68];
    int t = threadIdx.x;
    int tr = t>>4, tc4 = (t&15)*4;
    for(int it=0; it<4; it++){
        int r = it*16 + tr;
        f32x4 vv = *reinterpret_cast<const f32x4*>(src + (size_t)(r0+r)*sstr + c0 + tc4);
        s16x4 p; p[0]=(short)f2bf(vv[0]); p[1]=(short)f2bf(vv[1]);
                 p[2]=(short)f2bf(vv[2]); p[3]=(short)f2bf(vv[3]);
        *reinterpret_cast<s16x4*>(&T[r*68 + tc4]) = p;
    }
    __syncthreads();
    for(int it=0; it<4; it++){
        int c = it*16 + tr;
        s16x4 p;
        p[0] = (short)T[(tc4+0)*68 + c];
        p[1] = (short)T[(tc4+1)*68 + c];
        p[2] = (short)T[(tc4+2)*68 + c];
        p[3] = (short)T[(tc4+3)*68 + c];
        *reinterpret_cast<s16x4*>(dst + (size_t)(c0+c)*ND + r0 + tc4) = p;
    }
}

// ---------------- fused projections: z=0 Qproj, z=1 Kproj, z=2 V^Tproj --
// Register-prefetch pipeline: LOAD(t+1) issues before MFMA(t); regs->LDS
// after the post-MFMA barrier.
#define LDP 72
#define CPT 136
__global__ __launch_bounds__(256) void gemm_fused(
    const float* __restrict__ qf, const float* __restrict__ kf,
    const float* __restrict__ vf,
    const unsigned short* __restrict__ wq, const unsigned short* __restrict__ wk,
    const unsigned short* __restrict__ wv,
    unsigned short* __restrict__ oq, unsigned short* __restrict__ ok,
    unsigned short* __restrict__ ov){
    const int z = blockIdx.z;
    __shared__ alignas(16) unsigned short smem[2*128*LDP]; // 36864 B, aliased
    unsigned short* As = smem;
    unsigned short* Bs = smem + 128*LDP;
    int tid = threadIdx.x;
    int lane = tid & 63, wave = tid >> 6;
    int l15 = lane & 15, quad = lane >> 4;
    int wm = (wave >> 1)*64, wn = (wave & 1)*64;
    const int srow = tid >> 3, scb = tid & 7;   // staging row/col-block

    if(z < 2){
        // -------- Q/K projection: C[128x128] = cast(X) * Wt^T --------
        const float* Af          = z==0 ? qf : kf;
        const unsigned short* Bt = z==0 ? wq : wk;
        unsigned short* dst      = z==0 ? oq : ok;
        const float qsc          = z==0 ? QSCALE : 1.0f;
        int tm = blockIdx.x*128, tn = blockIdx.y*128;

        f32x4 ra0[4], ra1[4]; short8 rb[4];
        #define LOADQK(KK)                                                        \
        {   int k0 = (KK)*64;                                                     \
            _Pragma("unroll")                                                     \
            for(int i=0;i<4;i++){                                                 \
                int row = i*32 + srow;                                            \
                ra0[i] = *reinterpret_cast<const f32x4*>(Af + (size_t)(tm+row)*ND + k0 + scb*8);     \
                ra1[i] = *reinterpret_cast<const f32x4*>(Af + (size_t)(tm+row)*ND + k0 + scb*8 + 4); \
                rb[i]  = *reinterpret_cast<const short8*>(Bt + (size_t)(tn+row)*ND + k0 + scb*8);    \
            }                                                                     \
        }
        #define STOREQK                                                           \
        {   _Pragma("unroll")                                                     \
            for(int i=0;i<4;i++){                                                 \
                int row = i*32 + srow;                                            \
                *reinterpret_cast<short8*>(&As[row*LDP + scb*8]) = pack8(ra0[i], ra1[i]); \
                *reinterpret_cast<short8*>(&Bs[row*LDP + scb*8]) = rb[i];         \
            }                                                                     \
        }

        f32x4 acc[4][4] = {};
        LOADQK(0)
        STOREQK
        __syncthreads();
        LOADQK(1)
        for(int kk = 0; kk < 12; kk++){
            for(int ks = 0; ks < 2; ks++){
                short8 af[4], bf[4];
                for(int i = 0; i < 4; i++)
                    af[i] = *reinterpret_cast<const short8*>(&As[(wm + i*16 + l15)*LDP + ks*32 + quad*8]);
                for(int j = 0; j < 4; j++)
                    bf[j] = *reinterpret_cast<const short8*>(&Bs[(wn + j*16 + l15)*LDP + ks*32 + quad*8]);
                for(int i = 0; i < 4; i++)
                    for(int j = 0; j < 4; j++)
                        acc[i][j] = __builtin_amdgcn_mfma_f32_16x16x32_bf16(af[i], bf[j], acc[i][j], 0, 0, 0);
            }
            if(kk < 11){
                __syncthreads();      // readers done
                STOREQK               // tile kk+1 -> LDS
                __syncthreads();      // visible
                if(kk + 2 <= 11) LOADQK(kk+2)
            }
        }
        __syncthreads();
        unsigned short* Cs = smem;   // [128][CPT]
        for(int i = 0; i < 4; i++)
            for(int j = 0; j < 4; j++)
                for(int r = 0; r < 4; r++)
                    Cs[(wm + i*16 + quad*4 + r)*CPT + wn + j*16 + l15] = f2bf(acc[i][j][r]*qsc);
        __syncthreads();
        for(int c8 = 0; c8 < 8; c8++){
            int idx = c8*256 + tid;
            int row = idx >> 4, ch = idx & 15;
            short8 val = *reinterpret_cast<const short8*>(&Cs[row*CPT + ch*8]);
            int m = tm + row, n = tn + ch*8;
            int b = m >> 11, s = m & 2047, h = n >> 6, kk2 = n & 63;
            *reinterpret_cast<short8*>(dst + ((size_t)(b*NH + h)*NS + s)*HD + kk2) = val;
        }
        #undef LOADQK
        #undef STOREQK
    } else {
        // -------- V^T projection (operand-swapped): A=wv bf16, B=values f32
        int tm = blockIdx.y*128;   // 0..5  (wv rows h*64+kk)
        int tn = blockIdx.x*128;   // 0..63 (B*S rows)

        short8 rawv[4]; f32x4 rb0[4], rb1[4];
        #define LOADVT(KK)                                                        \
        {   int k0 = (KK)*64;                                                     \
            _Pragma("unroll")                                                     \
            for(int i=0;i<4;i++){                                                 \
                int row = i*32 + srow;                                            \
                rawv[i] = *reinterpret_cast<const short8*>(wv + (size_t)(tm+row)*ND + k0 + scb*8);  \
                rb0[i] = *reinterpret_cast<const f32x4*>(vf + (size_t)(tn+row)*ND + k0 + scb*8);    \
                rb1[i] = *reinterpret_cast<const f32x4*>(vf + (size_t)(tn+row)*ND + k0 + scb*8 + 4);\
            }                                                                     \
        }
        #define STOREVT                                                           \
        {   _Pragma("unroll")                                                     \
            for(int i=0;i<4;i++){                                                 \
                int row = i*32 + srow;                                            \
                *reinterpret_cast<short8*>(&As[row*LDP + scb*8]) = rawv[i];       \
                *reinterpret_cast<short8*>(&Bs[row*LDP + scb*8]) = pack8(rb0[i], rb1[i]); \
            }                                                                     \
        }

        f32x4 acc[4][4] = {};
        LOADVT(0)
        STOREVT
        __syncthreads();
        LOADVT(1)
        for(int kk = 0; kk < 12; kk++){
            for(int ks = 0; ks < 2; ks++){
                short8 af[4], bf[4];
                for(int i = 0; i < 4; i++)
                    af[i] = *reinterpret_cast<const short8*>(&As[(wm + i*16 + l15)*LDP + ks*32 + quad*8]);
                for(int j = 0; j < 4; j++)
                    bf[j] = *reinterpret_cast<const short8*>(&Bs[(wn + j*16 + l15)*LDP + ks*32 + quad*8]);
                for(int i = 0; i < 4; i++)
                    for(int j = 0; j < 4; j++)
                        acc[i][j] = __builtin_amdgcn_mfma_f32_16x16x32_bf16(af[i], bf[j], acc[i][j], 0, 0, 0);
            }
            if(kk < 11){
                __syncthreads();
                STOREVT
                __syncthreads();
                if(kk + 2 <= 11) LOADVT(kk+2)
            }
        }
        __syncthreads();
        unsigned short* Cs = smem;   // [128 rows=m][CPT cols=n]
        for(int i = 0; i < 4; i++)
            for(int j = 0; j < 4; j++)
                for(int r = 0; r < 4; r++)
                    Cs[(wm + i*16 + quad*4 + r)*CPT + wn + j*16 + l15] = f2bf(acc[i][j][r]);
        __syncthreads();
        int b = tn >> 11, s0 = tn & 2047;
        for(int c8 = 0; c8 < 8; c8++){
            int idx = c8*256 + tid;
            int row = idx >> 4, ch = idx & 15;
            short8 val = *reinterpret_cast<const short8*>(&Cs[row*CPT + ch*8]);
            int h = (tm + row) >> 6, kk2 = (tm + row) & 63;
            *reinterpret_cast<short8*>(ov + ((size_t)(b*NH + h)*HD + kk2)*NS + s0 + ch*8) = val;
        }
        #undef LOADVT
        #undef STOREVT
    }
}

// ---------------- flash attention: 32x32 MFMA, in-reg softmax, pipelined --
// grid (16, 48): x = 128-row q-tile, y = b*H+h. 4 waves x 32 q-rows.
// Iter t: stage(t); barrier; QK(t) -> z2; PV(t-1); softmax(t) -> afragP.
// hasBias path computes bias on the fly from mask: fmaf(1-m, NLOG2E, z).
__global__ __launch_bounds__(256, 3) void attn3_kernel(
    const unsigned short* __restrict__ qws, const unsigned short* __restrict__ kws,
    const unsigned short* __restrict__ vtws, const float* __restrict__ mask,
    const unsigned* __restrict__ bflag, unsigned short* __restrict__ ows){
    const int bh = blockIdx.y, qt = blockIdx.x;
    const int tid = threadIdx.x, lane = tid & 63, wave = tid >> 6;
    const int l31 = lane & 31, hi = lane >> 5;

    __shared__ alignas(16) unsigned short Ks[2][64*72];   // 18432 B
    __shared__ alignas(16) unsigned short Vs[3][64*72];   // 27648 B (total 46080)

    const size_t bhq = (size_t)bh * NS;
    const int qb0 = qt*128 + wave*32;
    const bool hasBias = (*bflag != 0u);   // uniform

    short8 bq[4];
    #pragma unroll
    for(int ds=0; ds<4; ds++)
        bq[ds] = *reinterpret_cast<const short8*>(
            qws + (bhq + qb0 + l31)*HD + ds*16 + hi*8);

    // mask row pointer: row = q_global, col base = hi*4
    const float* mp = mask + (size_t)(qb0 + l31)*NS + hi*4;

    const int rS = tid >> 3;       // 0..31
    const int cS = tid & 7;        // 0..7

    short8 rk[2], rv[2];
    #define LOADK(i,KT) rk[i] = *reinterpret_cast<const short8*>(kws + (bhq + (size_t)(KT)*64 + (i)*32 + rS)*HD + cS*8)
    #define LOADV(i,KT) rv[i] = *reinterpret_cast<const short8*>(vtws + ((size_t)bh*HD + (i)*32 + rS)*NS + (size_t)(KT)*64 + cS*8)

    #define STAGE(KB, VB)                                                         \
    {                                                                             \
        _Pragma("unroll")                                                         \
        for(int i=0;i<2;i++){                                                     \
            int row = i*32 + rS;                                                  \
            *reinterpret_cast<short8*>(&Ks[KB][row*72 + cS*8]) = rk[i];           \
            *reinterpret_cast<short8*>(&Vs[VB][row*72 + cS*8]) = rv[i];           \
        }                                                                         \
    }

    #define QK(KB)                                                                \
    {                                                                             \
        _Pragma("unroll")                                                         \
        for(int kb=0; kb<2; kb++){                                                \
            f32x16 zt = {};                                                       \
            _Pragma("unroll")                                                     \
            for(int ds=0; ds<4; ds++){                                            \
                short8 ak = *reinterpret_cast<const short8*>(                     \
                    &Ks[KB][(kb*32 + l31)*72 + ds*16 + hi*8]);                    \
                zt = __builtin_amdgcn_mfma_f32_32x32x16_bf16(ak, bq[ds], zt, 0, 0, 0);\
            }                                                                     \
            z2[kb] = zt;                                                          \
        }                                                                         \
    }

    #define SMAX(KT)                                                              \
    {                                                                             \
        _Pragma("unroll")                                                         \
        for(int kb=0; kb<2; kb++){                                                \
            unsigned p[8];                                                        \
            if(hasBias){                                                          \
                _Pragma("unroll")                                                 \
                for(int g=0; g<4; g++){                                           \
                    f32x4 mm = *reinterpret_cast<const f32x4*>(mp + (KT)*64 + kb*32 + g*8);\
                    float e0 = fexp2(fmaf(1.0f - mm[0], NLOG2E, z2[kb][g*4+0]));  \
                    float e1 = fexp2(fmaf(1.0f - mm[1], NLOG2E, z2[kb][g*4+1]));  \
                    float e2 = fexp2(fmaf(1.0f - mm[2], NLOG2E, z2[kb][g*4+2]));  \
                    float e3 = fexp2(fmaf(1.0f - mm[3], NLOG2E, z2[kb][g*4+3]));  \
                    p[g*2+0] = cvtpk(e0, e1);                                     \
                    p[g*2+1] = cvtpk(e2, e3);                                     \
                }                                                                 \
            } else {                                                              \
                _Pragma("unroll")                                                 \
                for(int g=0; g<4; g++){                                           \
                    float e0 = fexp2(z2[kb][g*4+0]);                              \
                    float e1 = fexp2(z2[kb][g*4+1]);                              \
                    float e2 = fexp2(z2[kb][g*4+2]);                              \
                    float e3 = fexp2(z2[kb][g*4+3]);                              \
                    p[g*2+0] = cvtpk(e0, e1);                                     \
                    p[g*2+1] = cvtpk(e2, e3);                                     \
                }                                                                 \
            }                                                                     \
            int2v sA = __builtin_amdgcn_permlane32_swap((int)p[0], (int)p[2], false, false); \
            int2v sB = __builtin_amdgcn_permlane32_swap((int)p[1], (int)p[3], false, false); \
            int2v sC = __builtin_amdgcn_permlane32_swap((int)p[4], (int)p[6], false, false); \
            int2v sD = __builtin_amdgcn_permlane32_swap((int)p[5], (int)p[7], false, false); \
            int4v f0; f0[0]=sA[0]; f0[1]=sB[0]; f0[2]=sA[1]; f0[3]=sB[1];         \
            int4v f1; f1[0]=sC[0]; f1[1]=sD[0]; f1[2]=sC[1]; f1[3]=sD[1];         \
            afragP[kb*2+0] = __builtin_bit_cast(short8, f0);                      \
            afragP[kb*2+1] = __builtin_bit_cast(short8, f1);                      \
        }                                                                         \
    }

    #define PVACC(VB)                                                             \
    {                                                                             \
        _Pragma("unroll")                                                         \
        for(int kst=0; kst<4; kst++){                                             \
            zacc = __builtin_amdgcn_mfma_f32_32x32x16_bf16(afragP[kst], vone, zacc, 0, 0, 0); \
            _Pragma("unroll")                                                     \
            for(int nb=0; nb<2; nb++){                                            \
                short8 bv = *reinterpret_cast<const short8*>(                     \
                    &Vs[VB][(nb*32 + l31)*72 + kst*16 + hi*8]);                   \
                oacc[nb] = __builtin_amdgcn_mfma_f32_32x32x16_bf16(afragP[kst], bv, oacc[nb], 0, 0, 0); \
            }                                                                     \
        }                                                                         \
    }

    f32x16 oacc[2] = {};
    f32x16 zacc = {};
    f32x16 z2[2];
    short8 afragP[4];
    short8 vone;
    #pragma unroll
    for(int i=0;i<8;i++) vone[i] = (short)0x3F80;   // bf16 1.0

    LOADK(0,0); LOADK(1,0); LOADV(0,0); LOADV(1,0);
    STAGE(0, 0)
    __syncthreads();
    LOADK(0,1); LOADK(1,1); LOADV(0,1); LOADV(1,1);
    __builtin_amdgcn_s_setprio(1);
    QK(0)
    __builtin_amdgcn_s_setprio(0);
    SMAX(0)

    for(int kt = 1; kt < 32; kt++){
        const int cb = kt & 1;
        const int vb = kt % 3;
        const int vp = (kt-1) % 3;
        STAGE(cb, vb)
        __syncthreads();
        int ktn = kt < 31 ? kt+1 : 31;
        LOADK(0,ktn); LOADK(1,ktn); LOADV(0,ktn); LOADV(1,ktn);

        __builtin_amdgcn_s_setprio(1);
        QK(cb)
        PVACC(vp)
        __builtin_amdgcn_s_setprio(0);
        SMAX(kt)
    }
    {
        const int vp = 31 % 3;   // = 1
        __builtin_amdgcn_s_setprio(1);
        PVACC(vp)
        __builtin_amdgcn_s_setprio(0);
    }

    float inv[16];
    #pragma unroll
    for(int r=0;r<16;r++) inv[r] = 1.0f / zacc[r];
    #pragma unroll
    for(int nb=0;nb<2;nb++)
        #pragma unroll
        for(int r=0;r<16;r++){
            int q = qb0 + (r&3) + 8*(r>>2) + 4*hi;
            ows[(bhq + q)*HD + nb*32 + l31] = f2bf(oacc[nb][r]*inv[r]);
        }
    #undef LOADK
    #undef LOADV
    #undef STAGE
    #undef QK
    #undef SMAX
    #undef PVACC
}

// ---------------- output projection: 128(m) x 64(n) tiles, 768 blocks ----
// Register-prefetch pipeline (same as gemm_fused).
__global__ __launch_bounds__(256) void gemm_out(
    const unsigned short* __restrict__ A, const unsigned short* __restrict__ Bt,
    float* __restrict__ out){
    __shared__ alignas(16) unsigned short smem[(128+64)*LDP]; // 27648 B
    unsigned short* As = smem;              // [128][72]
    unsigned short* Bs = smem + 128*LDP;    // [64][72]
    int tid = threadIdx.x;
    int lane = tid & 63, wave = tid >> 6;
    int l15 = lane & 15, quad = lane >> 4;
    int wm = (wave >> 1)*64, wn = (wave & 1)*32;
    int tm = blockIdx.x*128, tn = blockIdx.y*64;
    const int srow = tid >> 3, scb = tid & 7;

    short8 rA[4], rB[2];
    #define LOADO(KK)                                                             \
    {   int k0 = (KK)*64;                                                         \
        _Pragma("unroll")                                                         \
        for(int i=0;i<4;i++)                                                      \
            rA[i] = *reinterpret_cast<const short8*>(A + (size_t)(tm + i*32 + srow)*ND + k0 + scb*8); \
        _Pragma("unroll")                                                         \
        for(int i=0;i<2;i++)                                                      \
            rB[i] = *reinterpret_cast<const short8*>(Bt + (size_t)(tn + i*32 + srow)*ND + k0 + scb*8);\
    }
    #define STOREO                                                                \
    {   _Pragma("unroll")                                                         \
        for(int i=0;i<4;i++)                                                      \
            *reinterpret_cast<short8*>(&As[(i*32 + srow)*LDP + scb*8]) = rA[i];   \
        _Pragma("unroll")                                                         \
        for(int i=0;i<2;i++)                                                      \
            *reinterpret_cast<short8*>(&Bs[(i*32 + srow)*LDP + scb*8]) = rB[i];   \
    }

    f32x4 acc[4][2] = {};
    LOADO(0)
    STOREO
    __syncthreads();
    LOADO(1)
    for(int kk = 0; kk < 12; kk++){
        for(int ks = 0; ks < 2; ks++){
            short8 af[4], bf[2];
            for(int i = 0; i < 4; i++)
                af[i] = *reinterpret_cast<const short8*>(&As[(wm + i*16 + l15)*LDP + ks*32 + quad*8]);
            for(int j = 0; j < 2; j++)
                bf[j] = *reinterpret_cast<const short8*>(&Bs[(wn + j*16 + l15)*LDP + ks*32 + quad*8]);
            for(int i = 0; i < 4; i++)
                for(int j = 0; j < 2; j++)
                    acc[i][j] = __builtin_amdgcn_mfma_f32_16x16x32_bf16(af[i], bf[j], acc[i][j], 0, 0, 0);
        }
        if(kk < 11){
            __syncthreads();
            STOREO
            __syncthreads();
            if(kk + 2 <= 11) LOADO(kk+2)
        }
    }
    for(int i = 0; i < 4; i++)
        for(int j = 0; j < 2; j++)
            for(int r = 0; r < 4; r++){
                int m = tm + wm + i*16 + quad*4 + r;
                int n = tn + wn + j*16 + l15;
                out[(size_t)m*ND + n] = acc[i][j][r];
            }
    #undef LOADO
    #undef STOREO
}

// ---------------- launcher ----------------
extern "C" void kernel_launch(void* const* d_in, const int* in_sizes, int n_in,
                              void* d_out, int out_size, void* d_ws, size_t ws_size,
                              hipStream_t stream){
    const float* q    = (const float*)d_in[0];
    const float* k    = (const float*)d_in[1];
    const float* v    = (const float*)d_in[2];
    const float* mask = (const float*)d_in[3];
    const float* Wq   = (const float*)d_in[4];
    const float* Wk   = (const float*)d_in[5];
    const float* Wv   = (const float*)d_in[6];
    const float* Wo   = (const float*)d_in[7];
    char* ws = (char*)d_ws;
    unsigned*       bflag = (unsigned*)(ws + OFF_FLAG);
    unsigned short* wqp= (unsigned short*)(ws + OFF_WQ);
    unsigned short* wkp= (unsigned short*)(ws + OFF_WK);
    unsigned short* wvp= (unsigned short*)(ws + OFF_WV);
    unsigned short* wop= (unsigned short*)(ws + OFF_WO);
    unsigned short* qw = (unsigned short*)(ws + OFF_Q);
    unsigned short* kw = (unsigned short*)(ws + OFF_K);
    unsigned short* vw = (unsigned short*)(ws + OFF_V);
    unsigned short* ow = (unsigned short*)(ws + OFF_O);

    packw_kernel<<<dim3(144, 4), 256, 0, stream>>>(Wq, Wk, Wv, Wo, wqp, wkp, wvp, wop, bflag);
    flag_kernel<<<dim3(1024), 256, 0, stream>>>(mask, bflag);
    gemm_fused<<<dim3(64, 6, 3), 256, 0, stream>>>(q, k, v, wqp, wkp, wvp, qw, kw, vw);
    attn3_kernel<<<dim3(16, 48), 256, 0, stream>>>(qw, kw, vw, mask, bflag, ow);
    gemm_out<<<dim3(64, 12), 256, 0, stream>>>(ow, wop, (float*)d_out);
}